// Round 1
// baseline (519.530 us; speedup 1.0000x reference)
//
#include <hip/hip_runtime.h>

// Problem constants
constexpr int B_    = 32;
constexpr int IN_N  = 32;
constexpr int IN_D  = 16;
constexpr int H_    = 14;   // 14x14 -> 196 pixels
constexpr int HO_   = 7;    // 7x7 -> 49 pixels
constexpr int HID_  = 64;
constexpr int J_    = 1568;   // 32*49 queries
constexpr int NK0_  = 2048;   // projected keys (32 caps * 64 hid)
constexpr int NK_   = 2097;   // + 49 rel rows

// ---------------------------------------------------------------------------
// Grouped 3x3 conv, 14x14, input = current_pose [b][n][y][x][d] (permuted load)
// out[b][g*16+oc][p] laid out flat as blk*3136 + oc*196 + p
__global__ __launch_bounds__(256) void k_conv14(const float* __restrict__ pose,
                                                const float* __restrict__ w,
                                                float* __restrict__ out) {
    int blk = blockIdx.x;          // b*32 + g
    int tid = threadIdx.x;
    __shared__ float patch[16 * 196];
    __shared__ float wl[16 * 16 * 9];

    const float* pin = pose + (size_t)blk * (196 * 16);
    for (int t = tid; t < 16 * 196; t += 256) {
        int p = t >> 4, ic = t & 15;          // global contiguous: [p][ic]
        patch[ic * 196 + p] = pin[t];
    }
    int g = blk & 31;
    const float* wp = w + (size_t)g * 2304;   // 16 oc * 16 ic * 9
    for (int t = tid; t < 2304; t += 256) wl[t] = wp[t];
    __syncthreads();

    float* po = out + (size_t)blk * (16 * 196);
    for (int t = tid; t < 16 * 196; t += 256) {
        int oc = t / 196, p = t % 196;
        int y = p / 14, x = p % 14;
        float acc = 0.f;
        const float* wrow = wl + oc * 144;
        for (int ic = 0; ic < 16; ++ic) {
            const float* pr = patch + ic * 196;
            const float* wr = wrow + ic * 9;
#pragma unroll
            for (int ky = 0; ky < 3; ++ky) {
                int yy = y + ky - 1;
                if ((unsigned)yy >= 14u) continue;
#pragma unroll
                for (int kx = 0; kx < 3; ++kx) {
                    int xx = x + kx - 1;
                    if ((unsigned)xx >= 14u) continue;
                    acc += pr[yy * 14 + xx] * wr[ky * 3 + kx];
                }
            }
        }
        po[t] = acc;
    }
}

// ---------------------------------------------------------------------------
// Grouped 3x3 conv, 7x7. perm=1: input is next_pose [b][n][y][x][d];
// perm=0: input is plain [b][512][49]. Output flat blk*784 + oc*49 + p.
__global__ __launch_bounds__(256) void k_conv7(const float* __restrict__ in,
                                               const float* __restrict__ w,
                                               float* __restrict__ out, int perm) {
    int blk = blockIdx.x;          // b*32 + g
    int tid = threadIdx.x;
    __shared__ float patch[16 * 49];
    __shared__ float wl[2304];

    const float* pin = in + (size_t)blk * 784;
    if (perm) {
        for (int t = tid; t < 784; t += 256) {
            int p = t >> 4, ic = t & 15;
            patch[ic * 49 + p] = pin[t];
        }
    } else {
        for (int t = tid; t < 784; t += 256) patch[t] = pin[t];
    }
    int g = blk & 31;
    const float* wp = w + (size_t)g * 2304;
    for (int t = tid; t < 2304; t += 256) wl[t] = wp[t];
    __syncthreads();

    float* po = out + (size_t)blk * 784;
    for (int t = tid; t < 784; t += 256) {
        int oc = t / 49, p = t % 49;
        int y = p / 7, x = p % 7;
        float acc = 0.f;
        const float* wrow = wl + oc * 144;
        for (int ic = 0; ic < 16; ++ic) {
            const float* pr = patch + ic * 49;
            const float* wr = wrow + ic * 9;
#pragma unroll
            for (int ky = 0; ky < 3; ++ky) {
                int yy = y + ky - 1;
                if ((unsigned)yy >= 7u) continue;
#pragma unroll
                for (int kx = 0; kx < 3; ++kx) {
                    int xx = x + kx - 1;
                    if ((unsigned)xx >= 7u) continue;
                    acc += pr[yy * 7 + xx] * wr[ky * 3 + kx];
                }
            }
        }
        po[t] = acc;
    }
}

// ---------------------------------------------------------------------------
// Linformer key projection: K[b][m*64+h][e] = sum_p cpconv[b][e*32+m][p]*E[m][p][h]
// plus rel rows K[b][2048+r][e] = rel[e][r].  grid = B * 33 (m==32 -> rel fill)
__global__ __launch_bounds__(256) void k_kproj(const float* __restrict__ cpconv,
                                               const float* __restrict__ eproj,
                                               const float* __restrict__ rel,
                                               float* __restrict__ K) {
    int blk = blockIdx.x;
    int m = blk % 33, b = blk / 33;
    int tid = threadIdx.x;
    if (m == 32) {
        for (int t = tid; t < 49 * 16; t += 256) {
            int r = t >> 4, e = t & 15;
            K[(size_t)b * (NK_ * 16) + (size_t)(2048 + r) * 16 + e] = rel[e * 49 + r];
        }
        return;
    }
    __shared__ float ep[196 * 64];   // 50 KB
    __shared__ float cr[16 * 196];   // 12.5 KB
    const float* eb = eproj + (size_t)m * (196 * 64);
    for (int t = tid; t < 196 * 64; t += 256) ep[t] = eb[t];
    for (int t = tid; t < 16 * 196; t += 256) {
        int e = t / 196, p = t % 196;
        cr[t] = cpconv[(size_t)b * 100352 + (size_t)(e * 32 + m) * 196 + p];
    }
    __syncthreads();

    int e  = tid >> 4;         // 0..15
    int h4 = (tid & 15) * 4;   // 0,4,..,60
    float4 acc = {0.f, 0.f, 0.f, 0.f};
    const float* crr = cr + e * 196;
    for (int p = 0; p < 196; ++p) {
        float c = crr[p];
        float4 v = *(const float4*)(ep + p * 64 + h4);
        acc.x += c * v.x; acc.y += c * v.y; acc.z += c * v.z; acc.w += c * v.w;
    }
    size_t kb = (size_t)b * (NK_ * 16) + (size_t)(m * 64 + h4) * 16 + e;
    K[kb]      = acc.x;
    K[kb + 16] = acc.y;
    K[kb + 32] = acc.z;
    K[kb + 48] = acc.w;
}

// ---------------------------------------------------------------------------
// Column softmax stats over queries j: per (b,i) max_j S and 1/sum_j exp(S-m).
// Block: 32 i * 8 j-sublanes. Q tiles (64 j x 16) staged in LDS (stride 20).
__global__ __launch_bounds__(256) void k_stats(const float* __restrict__ Q,
                                               const float* __restrict__ K,
                                               float* __restrict__ colmax,
                                               float* __restrict__ colrl) {
    int blk = blockIdx.x;
    int it = blk % 66, b = blk / 66;
    int tid = threadIdx.x;
    int il = tid >> 3, jsub = tid & 7;
    int i = it * 32 + il;
    __shared__ float q[64 * 20];

    float4 k0 = {0,0,0,0}, k1 = k0, k2 = k0, k3 = k0;
    if (i < NK_) {
        const float4* kr = (const float4*)(K + (size_t)b * (NK_ * 16) + (size_t)i * 16);
        k0 = kr[0]; k1 = kr[1]; k2 = kr[2]; k3 = kr[3];
    }
    float rm = -1e30f, rl = 0.f;
    const float* Qb = Q + (size_t)b * 25088;

    for (int c = 0; c < 25; ++c) {
        int jbase = c * 64;
        __syncthreads();
        for (int t = tid; t < 1024; t += 256) {
            int jl = t >> 4, e = t & 15;
            int j = jbase + jl;
            if (j < J_) q[jl * 20 + e] = Qb[(size_t)j * 16 + e];
        }
        __syncthreads();
        for (int jl = jsub; jl < 64; jl += 8) {
            if (jbase + jl >= J_) break;
            const float4* qr = (const float4*)(q + jl * 20);
            float4 a = qr[0], bq = qr[1], cq = qr[2], dq = qr[3];
            float s = a.x*k0.x + a.y*k0.y + a.z*k0.z + a.w*k0.w
                    + bq.x*k1.x + bq.y*k1.y + bq.z*k1.z + bq.w*k1.w
                    + cq.x*k2.x + cq.y*k2.y + cq.z*k2.z + cq.w*k2.w
                    + dq.x*k3.x + dq.y*k3.y + dq.z*k3.z + dq.w*k3.w;
            s *= 0.25f;
            float nm = fmaxf(rm, s);
            rl = rl * __expf(rm - nm) + __expf(s - nm);
            rm = nm;
        }
    }
#pragma unroll
    for (int off = 1; off < 8; off <<= 1) {
        float om = __shfl_xor(rm, off, 8);
        float ol = __shfl_xor(rl, off, 8);
        float nm = fmaxf(rm, om);
        rl = rl * __expf(rm - nm) + ol * __expf(om - nm);
        rm = nm;
    }
    if (jsub == 0 && i < NK_) {
        colmax[(size_t)b * NK_ + i] = rm;
        colrl[(size_t)b * NK_ + i] = 1.0f / rl;
    }
}

// ---------------------------------------------------------------------------
// out[b][j][:] = sum_i exp(S[j,i]-m_i)*rl_i * K[i][:].  Block: 32 j * 8 i-sub.
__global__ __launch_bounds__(256) void k_pv(const float* __restrict__ Q,
                                            const float* __restrict__ K,
                                            const float* __restrict__ colmax,
                                            const float* __restrict__ colrl,
                                            float* __restrict__ outb) {
    int blk = blockIdx.x;
    int jt = blk % 49, b = blk / 49;
    int tid = threadIdx.x;
    int jl = tid >> 3, isub = tid & 7;
    int j = jt * 32 + jl;
    __shared__ float kl[64 * 20];
    __shared__ float ml[64];
    __shared__ float rl[64];

    const float4* qr = (const float4*)(Q + (size_t)b * 25088 + (size_t)j * 16);
    float4 q0 = qr[0], q1 = qr[1], q2 = qr[2], q3 = qr[3];
    float4 a0 = {0,0,0,0}, a1 = a0, a2 = a0, a3 = a0;
    const float* Kb = K + (size_t)b * (NK_ * 16);
    const float* mb = colmax + (size_t)b * NK_;
    const float* lb = colrl + (size_t)b * NK_;

    for (int c = 0; c < 33; ++c) {
        int ibase = c * 64;
        __syncthreads();
        for (int t = tid; t < 1024; t += 256) {
            int ilc = t >> 4, e = t & 15;
            int i = ibase + ilc;
            kl[ilc * 20 + e] = (i < NK_) ? Kb[(size_t)i * 16 + e] : 0.f;
        }
        if (tid < 64) {
            int i = ibase + tid;
            ml[tid] = (i < NK_) ? mb[i] : 0.f;
            rl[tid] = (i < NK_) ? lb[i] : 0.f;
        }
        __syncthreads();
        for (int il2 = isub; il2 < 64; il2 += 8) {
            int i = ibase + il2;
            if (i >= NK_) break;
            const float4* kr = (const float4*)(kl + il2 * 20);
            float4 b0 = kr[0], b1 = kr[1], b2 = kr[2], b3 = kr[3];
            float s = q0.x*b0.x + q0.y*b0.y + q0.z*b0.z + q0.w*b0.w
                    + q1.x*b1.x + q1.y*b1.y + q1.z*b1.z + q1.w*b1.w
                    + q2.x*b2.x + q2.y*b2.y + q2.z*b2.z + q2.w*b2.w
                    + q3.x*b3.x + q3.y*b3.y + q3.z*b3.z + q3.w*b3.w;
            float wgt = __expf(s * 0.25f - ml[il2]) * rl[il2];
            a0.x += wgt*b0.x; a0.y += wgt*b0.y; a0.z += wgt*b0.z; a0.w += wgt*b0.w;
            a1.x += wgt*b1.x; a1.y += wgt*b1.y; a1.z += wgt*b1.z; a1.w += wgt*b1.w;
            a2.x += wgt*b2.x; a2.y += wgt*b2.y; a2.z += wgt*b2.z; a2.w += wgt*b2.w;
            a3.x += wgt*b3.x; a3.y += wgt*b3.y; a3.z += wgt*b3.z; a3.w += wgt*b3.w;
        }
    }
#pragma unroll
    for (int off = 1; off < 8; off <<= 1) {
        a0.x += __shfl_xor(a0.x, off, 8); a0.y += __shfl_xor(a0.y, off, 8);
        a0.z += __shfl_xor(a0.z, off, 8); a0.w += __shfl_xor(a0.w, off, 8);
        a1.x += __shfl_xor(a1.x, off, 8); a1.y += __shfl_xor(a1.y, off, 8);
        a1.z += __shfl_xor(a1.z, off, 8); a1.w += __shfl_xor(a1.w, off, 8);
        a2.x += __shfl_xor(a2.x, off, 8); a2.y += __shfl_xor(a2.y, off, 8);
        a2.z += __shfl_xor(a2.z, off, 8); a2.w += __shfl_xor(a2.w, off, 8);
        a3.x += __shfl_xor(a3.x, off, 8); a3.y += __shfl_xor(a3.y, off, 8);
        a3.z += __shfl_xor(a3.z, off, 8); a3.w += __shfl_xor(a3.w, off, 8);
    }
    if (isub == 0) {
        float4* po = (float4*)(outb + (size_t)b * 25088 + (size_t)j * 16);
        po[0] = a0; po[1] = a1; po[2] = a2; po[3] = a3;
    }
}

// ---------------------------------------------------------------------------
// LayerNorm over consecutive groups of 16 floats (final reshape is identity).
__global__ __launch_bounds__(256) void k_ln(const float* __restrict__ x,
                                            const float* __restrict__ gamma,
                                            const float* __restrict__ beta,
                                            float* __restrict__ out, int ngroups) {
    int g = blockIdx.x * 256 + threadIdx.x;
    if (g >= ngroups) return;
    const float4* xp = (const float4*)(x + (size_t)g * 16);
    float4 x0 = xp[0], x1 = xp[1], x2 = xp[2], x3 = xp[3];
    float sum = x0.x + x0.y + x0.z + x0.w + x1.x + x1.y + x1.z + x1.w
              + x2.x + x2.y + x2.z + x2.w + x3.x + x3.y + x3.z + x3.w;
    float mu = sum * 0.0625f;
    float var = 0.f;
    var += (x0.x-mu)*(x0.x-mu) + (x0.y-mu)*(x0.y-mu) + (x0.z-mu)*(x0.z-mu) + (x0.w-mu)*(x0.w-mu);
    var += (x1.x-mu)*(x1.x-mu) + (x1.y-mu)*(x1.y-mu) + (x1.z-mu)*(x1.z-mu) + (x1.w-mu)*(x1.w-mu);
    var += (x2.x-mu)*(x2.x-mu) + (x2.y-mu)*(x2.y-mu) + (x2.z-mu)*(x2.z-mu) + (x2.w-mu)*(x2.w-mu);
    var += (x3.x-mu)*(x3.x-mu) + (x3.y-mu)*(x3.y-mu) + (x3.z-mu)*(x3.z-mu) + (x3.w-mu)*(x3.w-mu);
    float rstd = rsqrtf(var * 0.0625f + 1e-5f);
    const float4* gp = (const float4*)gamma;
    const float4* bp = (const float4*)beta;
    float4 g0 = gp[0], g1 = gp[1], g2 = gp[2], g3 = gp[3];
    float4 be0 = bp[0], be1 = bp[1], be2 = bp[2], be3 = bp[3];
    float4 o0, o1, o2, o3;
    o0.x = (x0.x-mu)*rstd*g0.x + be0.x; o0.y = (x0.y-mu)*rstd*g0.y + be0.y;
    o0.z = (x0.z-mu)*rstd*g0.z + be0.z; o0.w = (x0.w-mu)*rstd*g0.w + be0.w;
    o1.x = (x1.x-mu)*rstd*g1.x + be1.x; o1.y = (x1.y-mu)*rstd*g1.y + be1.y;
    o1.z = (x1.z-mu)*rstd*g1.z + be1.z; o1.w = (x1.w-mu)*rstd*g1.w + be1.w;
    o2.x = (x2.x-mu)*rstd*g2.x + be2.x; o2.y = (x2.y-mu)*rstd*g2.y + be2.y;
    o2.z = (x2.z-mu)*rstd*g2.z + be2.z; o2.w = (x2.w-mu)*rstd*g2.w + be2.w;
    o3.x = (x3.x-mu)*rstd*g3.x + be3.x; o3.y = (x3.y-mu)*rstd*g3.y + be3.y;
    o3.z = (x3.z-mu)*rstd*g3.z + be3.z; o3.w = (x3.w-mu)*rstd*g3.w + be3.w;
    float4* op = (float4*)(out + (size_t)g * 16);
    op[0] = o0; op[1] = o1; op[2] = o2; op[3] = o3;
}

// ---------------------------------------------------------------------------
extern "C" void kernel_launch(void* const* d_in, const int* in_sizes, int n_in,
                              void* d_out, int out_size, void* d_ws, size_t ws_size,
                              hipStream_t stream) {
    const float* current_pose = (const float*)d_in[0];
    const float* next_pose    = (const float*)d_in[1];
    const float* current_w    = (const float*)d_in[2];
    const float* next_w       = (const float*)d_in[3];
    const float* E_proj       = (const float*)d_in[4];
    const float* rel          = (const float*)d_in[5];
    const float* ln_gamma     = (const float*)d_in[6];
    const float* ln_beta      = (const float*)d_in[7];
    float* out = (float*)d_out;
    float* ws  = (float*)d_ws;

    // workspace layout (floats)
    float* cpconv = ws;                       // 32*512*196 = 3,211,264
    float* qconv  = ws + 3211264;             // 32*512*49  =   802,816  (== Q flat)
    float* Kmat   = ws + 4014080;             // 32*2097*16 = 1,073,664
    float* cmax   = ws + 5087744;             // 32*2097    =    67,104
    float* crl    = ws + 5154848;             // 32*2097    =    67,104
    float* atts   = ws + 5221952;             // 32*512*49  =   802,816
    float* conv2  = ws + 6024768;             // 32*512*49  =   802,816
    // total 6,827,584 floats = 27.3 MB

    k_conv14<<<B_ * 32, 256, 0, stream>>>(current_pose, current_w, cpconv);
    k_conv7 <<<B_ * 32, 256, 0, stream>>>(next_pose, next_w, qconv, 1);
    k_kproj <<<B_ * 33, 256, 0, stream>>>(cpconv, E_proj, rel, Kmat);
    k_stats <<<B_ * 66, 256, 0, stream>>>(qconv, Kmat, cmax, crl);
    k_pv    <<<B_ * 49, 256, 0, stream>>>(qconv, Kmat, cmax, crl, atts);
    k_conv7 <<<B_ * 32, 256, 0, stream>>>(atts, next_w, conv2, 0);
    k_ln    <<<(50176 + 255) / 256, 256, 0, stream>>>(conv2, ln_gamma, ln_beta, out, 50176);
}

// Round 2
// 369.896 us; speedup vs baseline: 1.4045x; 1.4045x over previous
//
#include <hip/hip_runtime.h>

typedef unsigned short u16;
typedef __attribute__((ext_vector_type(8))) short short8;   // 8 bf16 = 4 VGPRs
typedef __attribute__((ext_vector_type(4))) float floatx4;

#define MFMA16(a, b, c) __builtin_amdgcn_mfma_f32_16x16x32_bf16(a, b, c, 0, 0, 0)

__device__ inline u16 bf16rn(float x) {
    unsigned u = __float_as_uint(x);
    u += 0x7fffu + ((u >> 16) & 1u);
    return (u16)(u >> 16);
}
__device__ inline float bf16tof(u16 h) { return __uint_as_float(((unsigned)h) << 16); }
__device__ inline short8 ld8(const u16* p) { return *(const short8*)p; }

// ---------------------------------------------------------------------------
// Grouped 3x3 conv, 14x14, input = current_pose [b][n][y][x][d] (permuted load)
__global__ __launch_bounds__(256) void k_conv14(const float* __restrict__ pose,
                                                const float* __restrict__ w,
                                                float* __restrict__ out) {
    int blk = blockIdx.x;          // b*32 + g
    int tid = threadIdx.x;
    __shared__ float patch[16 * 196];
    __shared__ float wl[16 * 16 * 9];

    const float* pin = pose + (size_t)blk * (196 * 16);
    for (int t = tid; t < 16 * 196; t += 256) {
        int p = t >> 4, ic = t & 15;
        patch[ic * 196 + p] = pin[t];
    }
    int g = blk & 31;
    const float* wp = w + (size_t)g * 2304;
    for (int t = tid; t < 2304; t += 256) wl[t] = wp[t];
    __syncthreads();

    float* po = out + (size_t)blk * (16 * 196);
    for (int t = tid; t < 16 * 196; t += 256) {
        int oc = t / 196, p = t % 196;
        int y = p / 14, x = p % 14;
        float acc = 0.f;
        const float* wrow = wl + oc * 144;
        for (int ic = 0; ic < 16; ++ic) {
            const float* pr = patch + ic * 196;
            const float* wr = wrow + ic * 9;
#pragma unroll
            for (int ky = 0; ky < 3; ++ky) {
                int yy = y + ky - 1;
                if ((unsigned)yy >= 14u) continue;
#pragma unroll
                for (int kx = 0; kx < 3; ++kx) {
                    int xx = x + kx - 1;
                    if ((unsigned)xx >= 14u) continue;
                    acc += pr[yy * 14 + xx] * wr[ky * 3 + kx];
                }
            }
        }
        po[t] = acc;
    }
}

// ---------------------------------------------------------------------------
// Grouped 3x3 conv, 7x7. perm=1: input is next_pose [b][n][y][x][d]
__global__ __launch_bounds__(256) void k_conv7(const float* __restrict__ in,
                                               const float* __restrict__ w,
                                               float* __restrict__ out, int perm) {
    int blk = blockIdx.x;
    int tid = threadIdx.x;
    __shared__ float patch[16 * 49];
    __shared__ float wl[2304];

    const float* pin = in + (size_t)blk * 784;
    if (perm) {
        for (int t = tid; t < 784; t += 256) {
            int p = t >> 4, ic = t & 15;
            patch[ic * 49 + p] = pin[t];
        }
    } else {
        for (int t = tid; t < 784; t += 256) patch[t] = pin[t];
    }
    int g = blk & 31;
    const float* wp = w + (size_t)g * 2304;
    for (int t = tid; t < 2304; t += 256) wl[t] = wp[t];
    __syncthreads();

    float* po = out + (size_t)blk * 784;
    for (int t = tid; t < 784; t += 256) {
        int oc = t / 49, p = t % 49;
        int y = p / 7, x = p % 7;
        float acc = 0.f;
        const float* wrow = wl + oc * 144;
        for (int ic = 0; ic < 16; ++ic) {
            const float* pr = patch + ic * 49;
            const float* wr = wrow + ic * 9;
#pragma unroll
            for (int ky = 0; ky < 3; ++ky) {
                int yy = y + ky - 1;
                if ((unsigned)yy >= 7u) continue;
#pragma unroll
                for (int kx = 0; kx < 3; ++kx) {
                    int xx = x + kx - 1;
                    if ((unsigned)xx >= 7u) continue;
                    acc += pr[yy * 7 + xx] * wr[ky * 3 + kx];
                }
            }
        }
        po[t] = acc;
    }
}

// ---------------------------------------------------------------------------
// Linformer key projection: K[b][m*64+h][e] = sum_p cpconv[b][e*32+m][p]*E[m][p][h]
__global__ __launch_bounds__(256) void k_kproj(const float* __restrict__ cpconv,
                                               const float* __restrict__ eproj,
                                               const float* __restrict__ rel,
                                               float* __restrict__ K) {
    int blk = blockIdx.x;
    int m = blk % 33, b = blk / 33;
    int tid = threadIdx.x;
    if (m == 32) {
        for (int t = tid; t < 49 * 16; t += 256) {
            int r = t >> 4, e = t & 15;
            K[(size_t)b * (2097 * 16) + (size_t)(2048 + r) * 16 + e] = rel[e * 49 + r];
        }
        return;
    }
    __shared__ float ep[196 * 64];
    __shared__ float cr[16 * 196];
    const float* eb = eproj + (size_t)m * (196 * 64);
    for (int t = tid; t < 196 * 64; t += 256) ep[t] = eb[t];
    for (int t = tid; t < 16 * 196; t += 256) {
        int e = t / 196, p = t % 196;
        cr[t] = cpconv[(size_t)b * 100352 + (size_t)(e * 32 + m) * 196 + p];
    }
    __syncthreads();

    int e  = tid >> 4;
    int h4 = (tid & 15) * 4;
    float4 acc = {0.f, 0.f, 0.f, 0.f};
    const float* crr = cr + e * 196;
    for (int p = 0; p < 196; ++p) {
        float c = crr[p];
        float4 v = *(const float4*)(ep + p * 64 + h4);
        acc.x += c * v.x; acc.y += c * v.y; acc.z += c * v.z; acc.w += c * v.w;
    }
    size_t kb = (size_t)b * (2097 * 16) + (size_t)(m * 64 + h4) * 16 + e;
    K[kb]      = acc.x;
    K[kb + 16] = acc.y;
    K[kb + 32] = acc.z;
    K[kb + 48] = acc.w;
}

// ---------------------------------------------------------------------------
// Convert Q (x0.25) and K to hi/lo bf16 splits; K padded 2097->2112 rows,
// plus transposed copies KhT/KlT [b][16 e][2112 i].
__global__ __launch_bounds__(256) void k_cvt(const float* __restrict__ qconv,
                                             const float* __restrict__ Kmat,
                                             u16* __restrict__ Qp,
                                             u16* __restrict__ Kh,
                                             u16* __restrict__ Kl,
                                             u16* __restrict__ KhT,
                                             u16* __restrict__ KlT) {
    int gid = blockIdx.x * 256 + threadIdx.x;
    if (blockIdx.x < 196) {                 // Q rows: [0, 50176)
        const float4* q4 = (const float4*)(qconv + (size_t)gid * 16);
        float4 t0 = q4[0], t1 = q4[1], t2 = q4[2], t3 = q4[3];
        float v[16] = {t0.x,t0.y,t0.z,t0.w, t1.x,t1.y,t1.z,t1.w,
                       t2.x,t2.y,t2.z,t2.w, t3.x,t3.y,t3.z,t3.w};
        unsigned hw[8], lw[8];
#pragma unroll
        for (int t = 0; t < 8; ++t) {
            float x0 = v[2*t] * 0.25f, x1 = v[2*t+1] * 0.25f;
            u16 h0 = bf16rn(x0), h1 = bf16rn(x1);
            u16 l0 = bf16rn(x0 - bf16tof(h0)), l1 = bf16rn(x1 - bf16tof(h1));
            hw[t] = (unsigned)h0 | ((unsigned)h1 << 16);
            lw[t] = (unsigned)l0 | ((unsigned)l1 << 16);
        }
        uint4* r4 = (uint4*)(Qp + (size_t)gid * 32);
        r4[0] = make_uint4(hw[0], hw[1], hw[2], hw[3]);
        r4[1] = make_uint4(hw[4], hw[5], hw[6], hw[7]);
        r4[2] = make_uint4(lw[0], lw[1], lw[2], lw[3]);
        r4[3] = make_uint4(lw[4], lw[5], lw[6], lw[7]);
    } else {                                // K rows: [0, 67584)
        int id = gid - 50176;
        int b = id / 2112, i = id % 2112;
        float v[16] = {0.f};
        if (i < 2097) {
            const float4* k4 = (const float4*)(Kmat + ((size_t)b * 2097 + i) * 16);
            float4 t0 = k4[0], t1 = k4[1], t2 = k4[2], t3 = k4[3];
            v[0]=t0.x; v[1]=t0.y; v[2]=t0.z; v[3]=t0.w;
            v[4]=t1.x; v[5]=t1.y; v[6]=t1.z; v[7]=t1.w;
            v[8]=t2.x; v[9]=t2.y; v[10]=t2.z; v[11]=t2.w;
            v[12]=t3.x; v[13]=t3.y; v[14]=t3.z; v[15]=t3.w;
        }
        u16 hi[16], lo[16];
#pragma unroll
        for (int e = 0; e < 16; ++e) {
            hi[e] = bf16rn(v[e]);
            lo[e] = bf16rn(v[e] - bf16tof(hi[e]));
        }
        unsigned hw[8], lw[8];
#pragma unroll
        for (int t = 0; t < 8; ++t) {
            hw[t] = (unsigned)hi[2*t] | ((unsigned)hi[2*t+1] << 16);
            lw[t] = (unsigned)lo[2*t] | ((unsigned)lo[2*t+1] << 16);
        }
        uint4* kh4 = (uint4*)(Kh + (size_t)id * 16);
        uint4* kl4 = (uint4*)(Kl + (size_t)id * 16);
        kh4[0] = make_uint4(hw[0], hw[1], hw[2], hw[3]);
        kh4[1] = make_uint4(hw[4], hw[5], hw[6], hw[7]);
        kl4[0] = make_uint4(lw[0], lw[1], lw[2], lw[3]);
        kl4[1] = make_uint4(lw[4], lw[5], lw[6], lw[7]);
        size_t tb = (size_t)b * 33792 + i;
#pragma unroll
        for (int e = 0; e < 16; ++e) {
            KhT[tb + e * 2112] = hi[e];
            KlT[tb + e * 2112] = lo[e];
        }
    }
}

// ---------------------------------------------------------------------------
// Column stats via MFMA: lr[b][i] = -log(sum_j exp(S[j,i])) ; padded i -> -1e30
__global__ __launch_bounds__(256) void k_stats2(const u16* __restrict__ Qp,
                                                const u16* __restrict__ Kh,
                                                const u16* __restrict__ Kl,
                                                float* __restrict__ lr) {
    int blk = blockIdx.x;
    int b = blk / 33, itb = blk % 33;
    int wave = threadIdx.x >> 6, lane = threadIdx.x & 63;
    int it = itb * 4 + wave;          // i-tile 0..131
    int ibase = it * 16;
    int n = lane & 15, quad = lane >> 4;

    size_t krow = ((size_t)b * 2112 + ibase + n) * 16 + (quad & 1) * 8;
    short8 bh = ld8(Kh + krow);
    short8 bl = ld8(Kl + krow);

    const u16* qb = Qp + (size_t)b * 50176 + n * 32 + quad * 8;
    floatx4 dacc = {0.f, 0.f, 0.f, 0.f};
    short8 a = ld8(qb);
    for (int jt = 0; jt < 98; ++jt) {
        short8 an = (jt < 97) ? ld8(qb + (size_t)(jt + 1) * 512) : a;
        floatx4 c = {0.f, 0.f, 0.f, 0.f};
        c = MFMA16(a, bh, c);
        c = MFMA16(a, bl, c);
        dacc.x += __expf(c.x); dacc.y += __expf(c.y);
        dacc.z += __expf(c.z); dacc.w += __expf(c.w);
        a = an;
    }
    float d = dacc.x + dacc.y + dacc.z + dacc.w;
    d += __shfl_xor(d, 16);
    d += __shfl_xor(d, 32);
    if (quad == 0) {
        int i = ibase + n;
        lr[(size_t)b * 2112 + i] = (i < 2097) ? -__logf(d) : -1e30f;
    }
}

// ---------------------------------------------------------------------------
// PV via MFMA with per-wave LDS W-transpose. out[b][j][e] = sum_i exp(S+lr_i)*K[i][e]
__global__ __launch_bounds__(256) void k_pv2(const u16* __restrict__ Qp,
                                             const u16* __restrict__ Kh,
                                             const u16* __restrict__ Kl,
                                             const u16* __restrict__ KhT,
                                             const u16* __restrict__ KlT,
                                             const float* __restrict__ lr,
                                             float* __restrict__ outb) {
    __shared__ __align__(16) u16 wt[4][2][16 * 40];
    int blk = blockIdx.x;
    int b = blk / 25, jtb = blk % 25;
    int wave = threadIdx.x >> 6, lane = threadIdx.x & 63;
    int jt = jtb * 4 + wave;
    if (jt >= 98) return;                  // no barriers below: safe early-exit
    int n = lane & 15, quad = lane >> 4;

    short8 aq = ld8(Qp + ((size_t)b * 1568 + jt * 16 + n) * 32 + quad * 8);
    u16* wh = &wt[wave][0][0];
    u16* wl = &wt[wave][1][0];
    const u16* khb = Kh + ((size_t)b * 2112 + n) * 16 + (quad & 1) * 8;
    const u16* klb = Kl + ((size_t)b * 2112 + n) * 16 + (quad & 1) * 8;
    const u16* kht = KhT + (size_t)b * 33792 + n * 2112 + quad * 8;
    const u16* klt = KlT + (size_t)b * 33792 + n * 2112 + quad * 8;
    const float* lrb = lr + (size_t)b * 2112 + n;

    floatx4 o = {0.f, 0.f, 0.f, 0.f};

    short8 c_sh0 = ld8(khb),       c_sl0 = ld8(klb);
    short8 c_sh1 = ld8(khb + 256), c_sl1 = ld8(klb + 256);
    short8 c_th  = ld8(kht),       c_tl  = ld8(klt);
    float  c_r0  = lrb[0],         c_r1  = lrb[16];

    for (int c = 0; c < 66; ++c) {
        short8 n_sh0, n_sl0, n_sh1, n_sl1, n_th, n_tl;
        float n_r0 = 0.f, n_r1 = 0.f;
        if (c < 65) {
            int ib = (c + 1) * 32;
            n_sh0 = ld8(khb + (size_t)ib * 16);
            n_sl0 = ld8(klb + (size_t)ib * 16);
            n_sh1 = ld8(khb + (size_t)(ib + 16) * 16);
            n_sl1 = ld8(klb + (size_t)(ib + 16) * 16);
            n_th  = ld8(kht + ib);
            n_tl  = ld8(klt + ib);
            n_r0  = lrb[ib]; n_r1 = lrb[ib + 16];
        }
        floatx4 s0 = {0.f, 0.f, 0.f, 0.f};
        s0 = MFMA16(aq, c_sh0, s0);
        s0 = MFMA16(aq, c_sl0, s0);
        floatx4 s1 = {0.f, 0.f, 0.f, 0.f};
        s1 = MFMA16(aq, c_sh1, s1);
        s1 = MFMA16(aq, c_sl1, s1);
#pragma unroll
        for (int r = 0; r < 4; ++r) {
            float w0 = __expf(s0[r] + c_r0);
            float w1 = __expf(s1[r] + c_r1);
            u16 h0 = bf16rn(w0), h1 = bf16rn(w1);
            int row = (quad * 4 + r) * 40;
            wh[row + n]      = h0;
            wh[row + 16 + n] = h1;
            wl[row + n]      = bf16rn(w0 - bf16tof(h0));
            wl[row + 16 + n] = bf16rn(w1 - bf16tof(h1));
        }
        asm volatile("s_waitcnt lgkmcnt(0)" ::: "memory");
        short8 awh = ld8(wh + n * 40 + quad * 8);
        short8 awl = ld8(wl + n * 40 + quad * 8);
        o = MFMA16(awh, c_th, o);
        o = MFMA16(awh, c_tl, o);
        o = MFMA16(awl, c_th, o);
        if (c < 65) {
            c_sh0 = n_sh0; c_sl0 = n_sl0; c_sh1 = n_sh1; c_sl1 = n_sl1;
            c_th = n_th; c_tl = n_tl; c_r0 = n_r0; c_r1 = n_r1;
        }
    }
    float* ob = outb + ((size_t)b * 1568 + (size_t)jt * 16) * 16;
#pragma unroll
    for (int r = 0; r < 4; ++r) ob[(quad * 4 + r) * 16 + n] = o[r];
}

// ---------------------------------------------------------------------------
// LayerNorm over consecutive groups of 16 floats.
__global__ __launch_bounds__(256) void k_ln(const float* __restrict__ x,
                                            const float* __restrict__ gamma,
                                            const float* __restrict__ beta,
                                            float* __restrict__ out, int ngroups) {
    int g = blockIdx.x * 256 + threadIdx.x;
    if (g >= ngroups) return;
    const float4* xp = (const float4*)(x + (size_t)g * 16);
    float4 x0 = xp[0], x1 = xp[1], x2 = xp[2], x3 = xp[3];
    float sum = x0.x + x0.y + x0.z + x0.w + x1.x + x1.y + x1.z + x1.w
              + x2.x + x2.y + x2.z + x2.w + x3.x + x3.y + x3.z + x3.w;
    float mu = sum * 0.0625f;
    float var = 0.f;
    var += (x0.x-mu)*(x0.x-mu) + (x0.y-mu)*(x0.y-mu) + (x0.z-mu)*(x0.z-mu) + (x0.w-mu)*(x0.w-mu);
    var += (x1.x-mu)*(x1.x-mu) + (x1.y-mu)*(x1.y-mu) + (x1.z-mu)*(x1.z-mu) + (x1.w-mu)*(x1.w-mu);
    var += (x2.x-mu)*(x2.x-mu) + (x2.y-mu)*(x2.y-mu) + (x2.z-mu)*(x2.z-mu) + (x2.w-mu)*(x2.w-mu);
    var += (x3.x-mu)*(x3.x-mu) + (x3.y-mu)*(x3.y-mu) + (x3.z-mu)*(x3.z-mu) + (x3.w-mu)*(x3.w-mu);
    float rstd = rsqrtf(var * 0.0625f + 1e-5f);
    const float4* gp = (const float4*)gamma;
    const float4* bp = (const float4*)beta;
    float4 g0 = gp[0], g1 = gp[1], g2 = gp[2], g3 = gp[3];
    float4 be0 = bp[0], be1 = bp[1], be2 = bp[2], be3 = bp[3];
    float4 o0, o1, o2, o3;
    o0.x = (x0.x-mu)*rstd*g0.x + be0.x; o0.y = (x0.y-mu)*rstd*g0.y + be0.y;
    o0.z = (x0.z-mu)*rstd*g0.z + be0.z; o0.w = (x0.w-mu)*rstd*g0.w + be0.w;
    o1.x = (x1.x-mu)*rstd*g1.x + be1.x; o1.y = (x1.y-mu)*rstd*g1.y + be1.y;
    o1.z = (x1.z-mu)*rstd*g1.z + be1.z; o1.w = (x1.w-mu)*rstd*g1.w + be1.w;
    o2.x = (x2.x-mu)*rstd*g2.x + be2.x; o2.y = (x2.y-mu)*rstd*g2.y + be2.y;
    o2.z = (x2.z-mu)*rstd*g2.z + be2.z; o2.w = (x2.w-mu)*rstd*g2.w + be2.w;
    o3.x = (x3.x-mu)*rstd*g3.x + be3.x; o3.y = (x3.y-mu)*rstd*g3.y + be3.y;
    o3.z = (x3.z-mu)*rstd*g3.z + be3.z; o3.w = (x3.w-mu)*rstd*g3.w + be3.w;
    float4* op = (float4*)(out + (size_t)g * 16);
    op[0] = o0; op[1] = o1; op[2] = o2; op[3] = o3;
}

// ---------------------------------------------------------------------------
extern "C" void kernel_launch(void* const* d_in, const int* in_sizes, int n_in,
                              void* d_out, int out_size, void* d_ws, size_t ws_size,
                              hipStream_t stream) {
    const float* current_pose = (const float*)d_in[0];
    const float* next_pose    = (const float*)d_in[1];
    const float* current_w    = (const float*)d_in[2];
    const float* next_w       = (const float*)d_in[3];
    const float* E_proj       = (const float*)d_in[4];
    const float* rel          = (const float*)d_in[5];
    const float* ln_gamma     = (const float*)d_in[6];
    const float* ln_beta      = (const float*)d_in[7];
    float* out = (float*)d_out;
    float* ws  = (float*)d_ws;

    // workspace layout (floats)
    float* cpconv = ws;                 // 3,211,264
    float* qconv  = ws + 3211264;       //   802,816  (== Q flat [b][1568][16])
    float* Kmat   = ws + 4014080;       // 1,073,664  (fp32 K, 2097 rows)
    float* atts   = ws + 5087744;       //   802,816
    float* conv2  = ws + 5890560;       //   802,816
    float* lr2    = ws + 6693376;       //    67,584  (32 x 2112)
    u16*   ub     = (u16*)(ws + 6760960);
    u16* Qp  = ub;                      // 32*1568*32 = 1,605,632
    u16* Kh  = ub + 1605632;            // 32*2112*16 = 1,081,344
    u16* Kl  = ub + 2686976;
    u16* KhT = ub + 3768320;            // 32*16*2112
    u16* KlT = ub + 4849664;
    // total ~38.9 MB

    k_conv14<<<1024, 256, 0, stream>>>(current_pose, current_w, cpconv);
    k_conv7 <<<1024, 256, 0, stream>>>(next_pose, next_w, qconv, 1);
    k_kproj <<<1056, 256, 0, stream>>>(cpconv, E_proj, rel, Kmat);
    k_cvt   <<<460,  256, 0, stream>>>(qconv, Kmat, Qp, Kh, Kl, KhT, KlT);
    k_stats2<<<1056, 256, 0, stream>>>(Qp, Kh, Kl, lr2);
    k_pv2   <<<800,  256, 0, stream>>>(Qp, Kh, Kl, KhT, KlT, lr2, atts);
    k_conv7 <<<1024, 256, 0, stream>>>(atts, next_w, conv2, 0);
    k_ln    <<<196,  256, 0, stream>>>(conv2, ln_gamma, ln_beta, out, 50176);
}

// Round 3
// 261.545 us; speedup vs baseline: 1.9864x; 1.4143x over previous
//
#include <hip/hip_runtime.h>

typedef unsigned short u16;
typedef __attribute__((ext_vector_type(8))) short short8;   // 8 bf16 = 4 VGPRs
typedef __attribute__((ext_vector_type(4))) float floatx4;

#define MFMA16(a, b, c) __builtin_amdgcn_mfma_f32_16x16x32_bf16(a, b, c, 0, 0, 0)

__device__ inline u16 bf16rn(float x) {
    unsigned u = __float_as_uint(x);
    u += 0x7fffu + ((u >> 16) & 1u);
    return (u16)(u >> 16);
}
__device__ inline float bf16tof(u16 h) { return __uint_as_float(((unsigned)h) << 16); }
__device__ inline short8 ld8(const u16* p) { return *(const short8*)p; }

// ---------------------------------------------------------------------------
// Grouped 3x3 conv 14x14. Halo-padded LDS patch (16 ic x 16x16), scalar weights.
__global__ __launch_bounds__(256) void k_conv14(const float* __restrict__ pose,
                                                const float* __restrict__ w,
                                                float* __restrict__ out) {
    int blk = blockIdx.x;  // b*32+g
    int tid = threadIdx.x;
    __shared__ float patch[16 * 256];
#pragma unroll
    for (int k = 0; k < 16; ++k) patch[k * 256 + tid] = 0.f;
    __syncthreads();
    const float* pin = pose + (size_t)blk * 3136;
    for (int t = tid; t < 3136; t += 256) {
        int p = t >> 4, ic = t & 15;
        int y = p / 14, x = p % 14;
        patch[ic * 256 + (y + 1) * 16 + (x + 1)] = pin[t];
    }
    __syncthreads();
    int g = blk & 31;
    const float* wg = w + (size_t)g * 2304;    // uniform -> s_load weights
    float* po = out + (size_t)blk * 3136;
    if (tid < 196) {
        int y = tid / 14, x = tid % 14;
        int base = (y + 1) * 16 + (x + 1);
        float acc[16];
#pragma unroll
        for (int oc = 0; oc < 16; ++oc) acc[oc] = 0.f;
        for (int ic = 0; ic < 16; ++ic) {
            const float* pr = patch + ic * 256 + base;
            float win[9];
#pragma unroll
            for (int ky = 0; ky < 3; ++ky)
#pragma unroll
                for (int kx = 0; kx < 3; ++kx)
                    win[ky * 3 + kx] = pr[(ky - 1) * 16 + (kx - 1)];
            const float* wi = wg + ic * 9;
#pragma unroll
            for (int oc = 0; oc < 16; ++oc)
#pragma unroll
                for (int kk = 0; kk < 9; ++kk)
                    acc[oc] += win[kk] * wi[oc * 144 + kk];
        }
#pragma unroll
        for (int oc = 0; oc < 16; ++oc) po[oc * 196 + tid] = acc[oc];
    }
}

// ---------------------------------------------------------------------------
// Grouped 3x3 conv 7x7, oc-split x2. mode=1: permuted pose input; mode=0: in+in2.
__global__ __launch_bounds__(64) void k_conv7(const float* __restrict__ in,
                                              const float* __restrict__ in2,
                                              const float* __restrict__ w,
                                              float* __restrict__ out, int mode) {
    int blk = blockIdx.x;          // (b*32+g)*2 + oh
    int oh = blk & 1, bg = blk >> 1;
    int tid = threadIdx.x;
    __shared__ float patch[16 * 144];
    for (int t = tid; t < 16 * 144; t += 64) patch[t] = 0.f;
    __syncthreads();
    const float* pin = in + (size_t)bg * 784;
    if (mode == 1) {
        for (int t = tid; t < 784; t += 64) {
            int p = t >> 4, ic = t & 15;
            int y = p / 7, x = p % 7;
            patch[ic * 144 + (y + 1) * 16 + (x + 1)] = pin[t];
        }
    } else {
        const float* pin2 = in2 + (size_t)bg * 784;
        for (int t = tid; t < 784; t += 64) {
            int ic = t / 49, p = t % 49;
            int y = p / 7, x = p % 7;
            patch[ic * 144 + (y + 1) * 16 + (x + 1)] = pin[t] + pin2[t];
        }
    }
    __syncthreads();
    int g = bg & 31;
    const float* wg = w + (size_t)g * 2304 + (size_t)oh * 8 * 144;
    float* po = out + (size_t)bg * 784 + (size_t)oh * 8 * 49;
    if (tid < 49) {
        int y = tid / 7, x = tid % 7;
        int base = (y + 1) * 16 + (x + 1);
        float acc[8];
#pragma unroll
        for (int oc = 0; oc < 8; ++oc) acc[oc] = 0.f;
        for (int ic = 0; ic < 16; ++ic) {
            const float* pr = patch + ic * 144 + base;
            float win[9];
#pragma unroll
            for (int ky = 0; ky < 3; ++ky)
#pragma unroll
                for (int kx = 0; kx < 3; ++kx)
                    win[ky * 3 + kx] = pr[(ky - 1) * 16 + (kx - 1)];
            const float* wi = wg + ic * 9;
#pragma unroll
            for (int oc = 0; oc < 8; ++oc)
#pragma unroll
                for (int kk = 0; kk < 9; ++kk)
                    acc[oc] += win[kk] * wi[oc * 144 + kk];
        }
#pragma unroll
        for (int oc = 0; oc < 8; ++oc) po[oc * 49 + tid] = acc[oc];
    }
}

// ---------------------------------------------------------------------------
// Linformer key projection (unchanged).
__global__ __launch_bounds__(256) void k_kproj(const float* __restrict__ cpconv,
                                               const float* __restrict__ eproj,
                                               const float* __restrict__ rel,
                                               float* __restrict__ K) {
    int blk = blockIdx.x;
    int m = blk % 33, b = blk / 33;
    int tid = threadIdx.x;
    if (m == 32) {
        for (int t = tid; t < 49 * 16; t += 256) {
            int r = t >> 4, e = t & 15;
            K[(size_t)b * (2097 * 16) + (size_t)(2048 + r) * 16 + e] = rel[e * 49 + r];
        }
        return;
    }
    __shared__ float ep[196 * 64];
    __shared__ float cr[16 * 196];
    const float* eb = eproj + (size_t)m * (196 * 64);
    for (int t = tid; t < 196 * 64; t += 256) ep[t] = eb[t];
    for (int t = tid; t < 16 * 196; t += 256) {
        int e = t / 196, p = t % 196;
        cr[t] = cpconv[(size_t)b * 100352 + (size_t)(e * 32 + m) * 196 + p];
    }
    __syncthreads();

    int e  = tid >> 4;
    int h4 = (tid & 15) * 4;
    float4 acc = {0.f, 0.f, 0.f, 0.f};
    const float* crr = cr + e * 196;
    for (int p = 0; p < 196; ++p) {
        float c = crr[p];
        float4 v = *(const float4*)(ep + p * 64 + h4);
        acc.x += c * v.x; acc.y += c * v.y; acc.z += c * v.z; acc.w += c * v.w;
    }
    size_t kb = (size_t)b * (2097 * 16) + (size_t)(m * 64 + h4) * 16 + e;
    K[kb]      = acc.x;
    K[kb + 16] = acc.y;
    K[kb + 32] = acc.z;
    K[kb + 48] = acc.w;
}

// ---------------------------------------------------------------------------
// Convert Q (x0.25) and K to hi/lo bf16 splits + transposed K copies (unchanged).
__global__ __launch_bounds__(256) void k_cvt(const float* __restrict__ qconv,
                                             const float* __restrict__ Kmat,
                                             u16* __restrict__ Qp,
                                             u16* __restrict__ Kh,
                                             u16* __restrict__ Kl,
                                             u16* __restrict__ KhT,
                                             u16* __restrict__ KlT) {
    int gid = blockIdx.x * 256 + threadIdx.x;
    if (blockIdx.x < 196) {                 // Q rows: [0, 50176)
        const float4* q4 = (const float4*)(qconv + (size_t)gid * 16);
        float4 t0 = q4[0], t1 = q4[1], t2 = q4[2], t3 = q4[3];
        float v[16] = {t0.x,t0.y,t0.z,t0.w, t1.x,t1.y,t1.z,t1.w,
                       t2.x,t2.y,t2.z,t2.w, t3.x,t3.y,t3.z,t3.w};
        unsigned hw[8], lw[8];
#pragma unroll
        for (int t = 0; t < 8; ++t) {
            float x0 = v[2*t] * 0.25f, x1 = v[2*t+1] * 0.25f;
            u16 h0 = bf16rn(x0), h1 = bf16rn(x1);
            u16 l0 = bf16rn(x0 - bf16tof(h0)), l1 = bf16rn(x1 - bf16tof(h1));
            hw[t] = (unsigned)h0 | ((unsigned)h1 << 16);
            lw[t] = (unsigned)l0 | ((unsigned)l1 << 16);
        }
        uint4* r4 = (uint4*)(Qp + (size_t)gid * 32);
        r4[0] = make_uint4(hw[0], hw[1], hw[2], hw[3]);
        r4[1] = make_uint4(hw[4], hw[5], hw[6], hw[7]);
        r4[2] = make_uint4(lw[0], lw[1], lw[2], lw[3]);
        r4[3] = make_uint4(lw[4], lw[5], lw[6], lw[7]);
    } else {                                // K rows: [0, 67584)
        int id = gid - 50176;
        int b = id / 2112, i = id % 2112;
        float v[16] = {0.f};
        if (i < 2097) {
            const float4* k4 = (const float4*)(Kmat + ((size_t)b * 2097 + i) * 16);
            float4 t0 = k4[0], t1 = k4[1], t2 = k4[2], t3 = k4[3];
            v[0]=t0.x; v[1]=t0.y; v[2]=t0.z; v[3]=t0.w;
            v[4]=t1.x; v[5]=t1.y; v[6]=t1.z; v[7]=t1.w;
            v[8]=t2.x; v[9]=t2.y; v[10]=t2.z; v[11]=t2.w;
            v[12]=t3.x; v[13]=t3.y; v[14]=t3.z; v[15]=t3.w;
        }
        u16 hi[16], lo[16];
#pragma unroll
        for (int e = 0; e < 16; ++e) {
            hi[e] = bf16rn(v[e]);
            lo[e] = bf16rn(v[e] - bf16tof(hi[e]));
        }
        unsigned hw[8], lw[8];
#pragma unroll
        for (int t = 0; t < 8; ++t) {
            hw[t] = (unsigned)hi[2*t] | ((unsigned)hi[2*t+1] << 16);
            lw[t] = (unsigned)lo[2*t] | ((unsigned)lo[2*t+1] << 16);
        }
        uint4* kh4 = (uint4*)(Kh + (size_t)id * 16);
        uint4* kl4 = (uint4*)(Kl + (size_t)id * 16);
        kh4[0] = make_uint4(hw[0], hw[1], hw[2], hw[3]);
        kh4[1] = make_uint4(hw[4], hw[5], hw[6], hw[7]);
        kl4[0] = make_uint4(lw[0], lw[1], lw[2], lw[3]);
        kl4[1] = make_uint4(lw[4], lw[5], lw[6], lw[7]);
        size_t tb = (size_t)b * 33792 + i;
#pragma unroll
        for (int e = 0; e < 16; ++e) {
            KhT[tb + e * 2112] = hi[e];
            KlT[tb + e * 2112] = lo[e];
        }
    }
}

// ---------------------------------------------------------------------------
// Column denominators, j-split x2, LDS-staged Q chunks, double-buffered.
// dpart[jh][b][2112] = sum_{j in half} exp(S[j,i])
__global__ __launch_bounds__(256) void k_stats3(const u16* __restrict__ Qp,
                                                const u16* __restrict__ Kh,
                                                const u16* __restrict__ Kl,
                                                float* __restrict__ dpart) {
    __shared__ __align__(16) u16 ql[2][640];   // 16 rows x 40 u16 (80B stride)
    int blk = blockIdx.x;
    int b = blk / 66; int r2 = blk % 66; int jh = r2 / 33; int itb = r2 % 33;
    int tid = threadIdx.x, wave = tid >> 6, lane = tid & 63;
    int n = lane & 15, quad = lane >> 4;
    int it = itb * 4 + wave;
    int ibase = it * 16;
    size_t krow = ((size_t)b * 2112 + ibase + n) * 16 + (quad & 1) * 8;
    short8 bh = ld8(Kh + krow);
    short8 bl = ld8(Kl + krow);
    int jt0 = jh * 49;
    const u16* Qb = Qp + (size_t)b * 50176;
    uint4 sreg;
    auto ldc = [&](int c) {
        if (tid < 64) sreg = *(const uint4*)(Qb + (size_t)(jt0 + c) * 512 + (tid >> 2) * 32 + (tid & 3) * 8);
    };
    auto stc = [&](int buf) {
        if (tid < 64) *(uint4*)(&ql[buf][(tid >> 2) * 40 + (tid & 3) * 8]) = sreg;
    };
    floatx4 dacc = {0.f, 0.f, 0.f, 0.f};
    ldc(0); stc(0); ldc(1);
    __syncthreads();
    for (int c = 0; c < 49; ++c) {
        if (c + 1 < 49) stc((c + 1) & 1);
        if (c + 2 < 49) ldc(c + 2);
        short8 a = ld8(&ql[c & 1][n * 40 + quad * 8]);
        floatx4 s = {0.f, 0.f, 0.f, 0.f};
        s = MFMA16(a, bh, s);
        s = MFMA16(a, bl, s);
        dacc.x += __expf(s.x); dacc.y += __expf(s.y);
        dacc.z += __expf(s.z); dacc.w += __expf(s.w);
        __syncthreads();
    }
    float d = dacc.x + dacc.y + dacc.z + dacc.w;
    d += __shfl_xor(d, 16);
    d += __shfl_xor(d, 32);
    if (quad == 0) dpart[(size_t)jh * 67584 + (size_t)b * 2112 + ibase + n] = d;
}

// ---------------------------------------------------------------------------
// PV: block-staged K chunks (LDS dbuf, shared by 4 jt-waves), i-split x2.
// opart[ih][b][j][e] = sum_{i in half} exp(S)*K[i][e]/(d0+d1)
__global__ __launch_bounds__(256) void k_pv3(const u16* __restrict__ Qp,
                                             const u16* __restrict__ Kh,
                                             const u16* __restrict__ Kl,
                                             const u16* __restrict__ KhT,
                                             const u16* __restrict__ KlT,
                                             const float* __restrict__ dpart,
                                             float* __restrict__ opart) {
    __shared__ __align__(16) u16 khl[2][768], kll[2][768];   // 32 rows x 24 u16
    __shared__ __align__(16) u16 khtl[2][640], kltl[2][640]; // 16 rows x 40 u16
    __shared__ __align__(16) u16 wt[4][2][640];              // per-wave W rows x 40
    __shared__ float rll[2][32];

    int blk = blockIdx.x;                  // b*50 + jtb*2 + ih
    int b = blk / 50; int rem = blk % 50; int jtb = rem >> 1; int ih = rem & 1;
    int tid = threadIdx.x, wave = tid >> 6, lane = tid & 63;
    int n = lane & 15, quad = lane >> 4;
    int jt = jtb * 4 + wave;
    int jtc = jt < 98 ? jt : 97;
    int i0 = ih * 1056;
    size_t bK = (size_t)b * 2112;
    size_t bT = (size_t)b * 33792;
    const float* d0p = dpart + bK;
    const float* d1p = dpart + 67584 + bK;

    short8 aq = ld8(Qp + ((size_t)b * 1568 + (size_t)jtc * 16 + n) * 32 + quad * 8);

    int role = tid >> 6, rt = tid & 63;
    uint4 sreg; float da = 0.f, db = 0.f;
    auto ldchunk = [&](int c) {
        int i0c = i0 + c * 32;
        if (role == 0)      sreg = *(const uint4*)(Kh  + (bK + i0c + (rt >> 1)) * 16 + (rt & 1) * 8);
        else if (role == 1) sreg = *(const uint4*)(Kl  + (bK + i0c + (rt >> 1)) * 16 + (rt & 1) * 8);
        else if (role == 2) sreg = *(const uint4*)(KhT + bT + (size_t)(rt >> 2) * 2112 + i0c + (rt & 3) * 8);
        else                sreg = *(const uint4*)(KlT + bT + (size_t)(rt >> 2) * 2112 + i0c + (rt & 3) * 8);
        if (tid < 32) { da = d0p[i0c + tid]; db = d1p[i0c + tid]; }
    };
    auto stchunk = [&](int buf) {
        if (role == 0)      *(uint4*)(&khl[buf][(rt >> 1) * 24 + (rt & 1) * 8]) = sreg;
        else if (role == 1) *(uint4*)(&kll[buf][(rt >> 1) * 24 + (rt & 1) * 8]) = sreg;
        else if (role == 2) *(uint4*)(&khtl[buf][(rt >> 2) * 40 + (rt & 3) * 8]) = sreg;
        else                *(uint4*)(&kltl[buf][(rt >> 2) * 40 + (rt & 3) * 8]) = sreg;
        if (tid < 32) rll[buf][tid] = 1.0f / (da + db);
    };

    floatx4 o = {0.f, 0.f, 0.f, 0.f};
    u16* wh = &wt[wave][0][0];
    u16* wl = &wt[wave][1][0];

    ldchunk(0); stchunk(0); ldchunk(1);
    __syncthreads();
    for (int c = 0; c < 33; ++c) {
        if (c + 1 < 33) stchunk((c + 1) & 1);
        if (c + 2 < 33) ldchunk(c + 2);
        const u16* khb = &khl[c & 1][0];
        const u16* klb = &kll[c & 1][0];
        const u16* thb = &khtl[c & 1][0];
        const u16* tlb = &kltl[c & 1][0];
        short8 sh0 = ld8(khb + n * 24 + (quad & 1) * 8);
        short8 sh1 = ld8(khb + (16 + n) * 24 + (quad & 1) * 8);
        short8 sl0 = ld8(klb + n * 24 + (quad & 1) * 8);
        short8 sl1 = ld8(klb + (16 + n) * 24 + (quad & 1) * 8);
        short8 th  = ld8(thb + n * 40 + quad * 8);
        short8 tl  = ld8(tlb + n * 40 + quad * 8);
        float rl0 = rll[c & 1][n], rl1 = rll[c & 1][n + 16];
        floatx4 s0 = {0.f, 0.f, 0.f, 0.f};
        s0 = MFMA16(aq, sh0, s0);
        s0 = MFMA16(aq, sl0, s0);
        floatx4 s1 = {0.f, 0.f, 0.f, 0.f};
        s1 = MFMA16(aq, sh1, s1);
        s1 = MFMA16(aq, sl1, s1);
#pragma unroll
        for (int r = 0; r < 4; ++r) {
            float w0 = __expf(s0[r]) * rl0;      // w >= 0
            float w1 = __expf(s1[r]) * rl1;
            unsigned u0 = __float_as_uint(w0), u1 = __float_as_uint(w1);
            float l0 = w0 - __uint_as_float(u0 & 0xffff0000u);   // exact residual
            float l1 = w1 - __uint_as_float(u1 & 0xffff0000u);
            int row = (quad * 4 + r) * 40;
            wh[row + n]      = (u16)(u0 >> 16);
            wh[row + 16 + n] = (u16)(u1 >> 16);
            wl[row + n]      = (u16)(__float_as_uint(l0) >> 16);
            wl[row + 16 + n] = (u16)(__float_as_uint(l1) >> 16);
        }
        asm volatile("s_waitcnt lgkmcnt(0)" ::: "memory");
        short8 awh = ld8(wh + n * 40 + quad * 8);
        short8 awl = ld8(wl + n * 40 + quad * 8);
        o = MFMA16(awh, th, o);
        o = MFMA16(awh, tl, o);
        o = MFMA16(awl, th, o);
        __syncthreads();
    }
    if (jt < 98) {
        float* ob = opart + (size_t)ih * 802816 + ((size_t)b * 1568 + (size_t)jt * 16) * 16;
#pragma unroll
        for (int r = 0; r < 4; ++r) ob[(quad * 4 + r) * 16 + n] = o[r];
    }
}

// ---------------------------------------------------------------------------
// LayerNorm over consecutive groups of 16 floats.
__global__ __launch_bounds__(256) void k_ln(const float* __restrict__ x,
                                            const float* __restrict__ gamma,
                                            const float* __restrict__ beta,
                                            float* __restrict__ out, int ngroups) {
    int g = blockIdx.x * 256 + threadIdx.x;
    if (g >= ngroups) return;
    const float4* xp = (const float4*)(x + (size_t)g * 16);
    float4 x0 = xp[0], x1 = xp[1], x2 = xp[2], x3 = xp[3];
    float sum = x0.x + x0.y + x0.z + x0.w + x1.x + x1.y + x1.z + x1.w
              + x2.x + x2.y + x2.z + x2.w + x3.x + x3.y + x3.z + x3.w;
    float mu = sum * 0.0625f;
    float var = 0.f;
    var += (x0.x-mu)*(x0.x-mu) + (x0.y-mu)*(x0.y-mu) + (x0.z-mu)*(x0.z-mu) + (x0.w-mu)*(x0.w-mu);
    var += (x1.x-mu)*(x1.x-mu) + (x1.y-mu)*(x1.y-mu) + (x1.z-mu)*(x1.z-mu) + (x1.w-mu)*(x1.w-mu);
    var += (x2.x-mu)*(x2.x-mu) + (x2.y-mu)*(x2.y-mu) + (x2.z-mu)*(x2.z-mu) + (x2.w-mu)*(x2.w-mu);
    var += (x3.x-mu)*(x3.x-mu) + (x3.y-mu)*(x3.y-mu) + (x3.z-mu)*(x3.z-mu) + (x3.w-mu)*(x3.w-mu);
    float rstd = rsqrtf(var * 0.0625f + 1e-5f);
    const float4* gp = (const float4*)gamma;
    const float4* bp = (const float4*)beta;
    float4 g0 = gp[0], g1 = gp[1], g2 = gp[2], g3 = gp[3];
    float4 be0 = bp[0], be1 = bp[1], be2 = bp[2], be3 = bp[3];
    float4 o0, o1, o2, o3;
    o0.x = (x0.x-mu)*rstd*g0.x + be0.x; o0.y = (x0.y-mu)*rstd*g0.y + be0.y;
    o0.z = (x0.z-mu)*rstd*g0.z + be0.z; o0.w = (x0.w-mu)*rstd*g0.w + be0.w;
    o1.x = (x1.x-mu)*rstd*g1.x + be1.x; o1.y = (x1.y-mu)*rstd*g1.y + be1.y;
    o1.z = (x1.z-mu)*rstd*g1.z + be1.z; o1.w = (x1.w-mu)*rstd*g1.w + be1.w;
    o2.x = (x2.x-mu)*rstd*g2.x + be2.x; o2.y = (x2.y-mu)*rstd*g2.y + be2.y;
    o2.z = (x2.z-mu)*rstd*g2.z + be2.z; o2.w = (x2.w-mu)*rstd*g2.w + be2.w;
    o3.x = (x3.x-mu)*rstd*g3.x + be3.x; o3.y = (x3.y-mu)*rstd*g3.y + be3.y;
    o3.z = (x3.z-mu)*rstd*g3.z + be3.z; o3.w = (x3.w-mu)*rstd*g3.w + be3.w;
    float4* op = (float4*)(out + (size_t)g * 16);
    op[0] = o0; op[1] = o1; op[2] = o2; op[3] = o3;
}

// ---------------------------------------------------------------------------
extern "C" void kernel_launch(void* const* d_in, const int* in_sizes, int n_in,
                              void* d_out, int out_size, void* d_ws, size_t ws_size,
                              hipStream_t stream) {
    const float* current_pose = (const float*)d_in[0];
    const float* next_pose    = (const float*)d_in[1];
    const float* current_w    = (const float*)d_in[2];
    const float* next_w       = (const float*)d_in[3];
    const float* E_proj       = (const float*)d_in[4];
    const float* rel          = (const float*)d_in[5];
    const float* ln_gamma     = (const float*)d_in[6];
    const float* ln_beta      = (const float*)d_in[7];
    float* out = (float*)d_out;
    float* ws  = (float*)d_ws;

    // workspace layout (floats); region0 (cpconv) is reused after k_kproj
    float* cpconv = ws;                 // 3,211,264
    float* conv2  = ws;                 // alias: written after cpconv's last read
    float* opart  = ws + 802816;        // 2 x 802,816
    float* dpart  = ws + 2408448;       // 2 x 67,584  (ends 2,543,616 < 3,211,264)
    float* qconv  = ws + 3211264;       //   802,816  (Q flat [b][1568][16])
    float* Kmat   = ws + 4014080;       // 1,073,664
    u16*   ub     = (u16*)(ws + 5087744);
    u16* Qp  = ub;                      // 32*1568*32 = 1,605,632
    u16* Kh  = ub + 1605632;            // 32*2112*16 = 1,081,344
    u16* Kl  = ub + 2686976;
    u16* KhT = ub + 3768320;            // 32*16*2112
    u16* KlT = ub + 4849664;
    // total ~32.2 MB

    k_conv14<<<1024, 256, 0, stream>>>(current_pose, current_w, cpconv);
    k_conv7 <<<2048, 64,  0, stream>>>(next_pose, next_pose, next_w, qconv, 1);
    k_kproj <<<1056, 256, 0, stream>>>(cpconv, E_proj, rel, Kmat);
    k_cvt   <<<460,  256, 0, stream>>>(qconv, Kmat, Qp, Kh, Kl, KhT, KlT);
    k_stats3<<<2112, 256, 0, stream>>>(Qp, Kh, Kl, dpart);
    k_pv3   <<<1600, 256, 0, stream>>>(Qp, Kh, Kl, KhT, KlT, dpart, opart);
    k_conv7 <<<2048, 64,  0, stream>>>(opart, opart + 802816, next_w, conv2, 0);
    k_ln    <<<196,  256, 0, stream>>>(conv2, ln_gamma, ln_beta, out, 50176);
}

// Round 4
// 244.962 us; speedup vs baseline: 2.1209x; 1.0677x over previous
//
#include <hip/hip_runtime.h>

typedef unsigned short u16;
typedef __attribute__((ext_vector_type(8))) short short8;   // 8 bf16 = 4 VGPRs
typedef __attribute__((ext_vector_type(4))) float floatx4;

#define MFMA16(a, b, c) __builtin_amdgcn_mfma_f32_16x16x32_bf16(a, b, c, 0, 0, 0)

__device__ inline u16 bf16rn(float x) {
    unsigned u = __float_as_uint(x);
    u += 0x7fffu + ((u >> 16) & 1u);
    return (u16)(u >> 16);
}
__device__ inline float bf16tof(u16 h) { return __uint_as_float(((unsigned)h) << 16); }
__device__ inline short8 ld8(const u16* p) { return *(const short8*)p; }

// ---------------------------------------------------------------------------
// Grouped 3x3 conv 14x14. Halo-padded LDS patch, scalar weights.
__global__ __launch_bounds__(256) void k_conv14(const float* __restrict__ pose,
                                                const float* __restrict__ w,
                                                float* __restrict__ out) {
    int blk = blockIdx.x;  // b*32+g
    int tid = threadIdx.x;
    __shared__ float patch[16 * 256];
#pragma unroll
    for (int k = 0; k < 16; ++k) patch[k * 256 + tid] = 0.f;
    __syncthreads();
    const float* pin = pose + (size_t)blk * 3136;
    for (int t = tid; t < 3136; t += 256) {
        int p = t >> 4, ic = t & 15;
        int y = p / 14, x = p % 14;
        patch[ic * 256 + (y + 1) * 16 + (x + 1)] = pin[t];
    }
    __syncthreads();
    int g = blk & 31;
    const float* wg = w + (size_t)g * 2304;
    float* po = out + (size_t)blk * 3136;
    if (tid < 196) {
        int y = tid / 14, x = tid % 14;
        int base = (y + 1) * 16 + (x + 1);
        float acc[16];
#pragma unroll
        for (int oc = 0; oc < 16; ++oc) acc[oc] = 0.f;
        for (int ic = 0; ic < 16; ++ic) {
            const float* pr = patch + ic * 256 + base;
            float win[9];
#pragma unroll
            for (int ky = 0; ky < 3; ++ky)
#pragma unroll
                for (int kx = 0; kx < 3; ++kx)
                    win[ky * 3 + kx] = pr[(ky - 1) * 16 + (kx - 1)];
            const float* wi = wg + ic * 9;
#pragma unroll
            for (int oc = 0; oc < 16; ++oc)
#pragma unroll
                for (int kk = 0; kk < 9; ++kk)
                    acc[oc] += win[kk] * wi[oc * 144 + kk];
        }
#pragma unroll
        for (int oc = 0; oc < 16; ++oc) po[oc * 196 + tid] = acc[oc];
    }
}

// ---------------------------------------------------------------------------
// Grouped 3x3 conv 7x7, oc-split x2. mode=1: permuted pose input; mode=0: in+in2.
__global__ __launch_bounds__(64) void k_conv7(const float* __restrict__ in,
                                              const float* __restrict__ in2,
                                              const float* __restrict__ w,
                                              float* __restrict__ out, int mode) {
    int blk = blockIdx.x;          // (b*32+g)*2 + oh
    int oh = blk & 1, bg = blk >> 1;
    int tid = threadIdx.x;
    __shared__ float patch[16 * 144];
    for (int t = tid; t < 16 * 144; t += 64) patch[t] = 0.f;
    __syncthreads();
    const float* pin = in + (size_t)bg * 784;
    if (mode == 1) {
        for (int t = tid; t < 784; t += 64) {
            int p = t >> 4, ic = t & 15;
            int y = p / 7, x = p % 7;
            patch[ic * 144 + (y + 1) * 16 + (x + 1)] = pin[t];
        }
    } else {
        const float* pin2 = in2 + (size_t)bg * 784;
        for (int t = tid; t < 784; t += 64) {
            int ic = t / 49, p = t % 49;
            int y = p / 7, x = p % 7;
            patch[ic * 144 + (y + 1) * 16 + (x + 1)] = pin[t] + pin2[t];
        }
    }
    __syncthreads();
    int g = bg & 31;
    const float* wg = w + (size_t)g * 2304 + (size_t)oh * 8 * 144;
    float* po = out + (size_t)bg * 784 + (size_t)oh * 8 * 49;
    if (tid < 49) {
        int y = tid / 7, x = tid % 7;
        int base = (y + 1) * 16 + (x + 1);
        float acc[8];
#pragma unroll
        for (int oc = 0; oc < 8; ++oc) acc[oc] = 0.f;
        for (int ic = 0; ic < 16; ++ic) {
            const float* pr = patch + ic * 144 + base;
            float win[9];
#pragma unroll
            for (int ky = 0; ky < 3; ++ky)
#pragma unroll
                for (int kx = 0; kx < 3; ++kx)
                    win[ky * 3 + kx] = pr[(ky - 1) * 16 + (kx - 1)];
            const float* wi = wg + ic * 9;
#pragma unroll
            for (int oc = 0; oc < 8; ++oc)
#pragma unroll
                for (int kk = 0; kk < 9; ++kk)
                    acc[oc] += win[kk] * wi[oc * 144 + kk];
        }
#pragma unroll
        for (int oc = 0; oc < 8; ++oc) po[oc * 49 + tid] = acc[oc];
    }
}

// ---------------------------------------------------------------------------
// E_proj transpose + bf16 hi/lo: EhT/ElT[m][h][224p] (pad p>=196 -> 0).
__global__ __launch_bounds__(256) void k_ecvt(const float* __restrict__ E,
                                              u16* __restrict__ EhT,
                                              u16* __restrict__ ElT) {
    __shared__ float ep[196 * 65];
    int m = blockIdx.x, tid = threadIdx.x;
    const float* eb = E + (size_t)m * 12544;
    for (int t = tid; t < 12544; t += 256) {
        int p = t >> 6, h = t & 63;
        ep[p * 65 + h] = eb[t];
    }
    __syncthreads();
    for (int t = tid; t < 64 * 224; t += 256) {
        int h = t / 224, p = t % 224;
        float v = (p < 196) ? ep[p * 65 + h] : 0.f;
        u16 hi = bf16rn(v);
        u16 lo = bf16rn(v - bf16tof(hi));
        EhT[(size_t)m * 14336 + t] = hi;
        ElT[(size_t)m * 14336 + t] = lo;
    }
}

// ---------------------------------------------------------------------------
// MFMA key projection: per (b,m): D[16e x 64h] = cp[16e x 196p] * E[m][196p x 64h].
// hi/lo bf16 3-product scheme. Writes Kh/Kl (row-major) + KhT/KlT (transposed).
__global__ __launch_bounds__(256) void k_kproj2(const float* __restrict__ cpconv,
                                                const u16* __restrict__ EhT,
                                                const u16* __restrict__ ElT,
                                                u16* __restrict__ Kh,
                                                u16* __restrict__ Kl,
                                                u16* __restrict__ KhT,
                                                u16* __restrict__ KlT) {
    int blk = blockIdx.x;           // b*32 + m
    int b = blk >> 5, m = blk & 31;
    int wave = threadIdx.x >> 6, lane = threadIdx.x & 63;
    int ht = wave;                  // h-tile 0..3
    int n = lane & 15, quad = lane >> 4;

    const float* arow = cpconv + ((size_t)b * 512 + (size_t)n * 32 + m) * 196;
    const u16* bhrow = EhT + ((size_t)m * 64 + ht * 16 + n) * 224;
    const u16* blrow = ElT + ((size_t)m * 64 + ht * 16 + n) * 224;

    floatx4 c = {0.f, 0.f, 0.f, 0.f};
#pragma unroll
    for (int pc = 0; pc < 7; ++pc) {
        int p0 = pc * 32 + quad * 8;
        float av[8];
        if (p0 <= 188) {
            float4 x = *(const float4*)(arow + p0);
            float4 y = *(const float4*)(arow + p0 + 4);
            av[0]=x.x; av[1]=x.y; av[2]=x.z; av[3]=x.w;
            av[4]=y.x; av[5]=y.y; av[6]=y.z; av[7]=y.w;
        } else {
#pragma unroll
            for (int k2 = 0; k2 < 8; ++k2) av[k2] = (p0 + k2 < 196) ? arow[p0 + k2] : 0.f;
        }
        short8 ah, al;
#pragma unroll
        for (int k2 = 0; k2 < 8; ++k2) {
            u16 h = bf16rn(av[k2]);
            ah[k2] = (short)h;
            al[k2] = (short)bf16rn(av[k2] - bf16tof(h));
        }
        short8 bh = ld8(bhrow + pc * 32 + quad * 8);
        short8 bl = ld8(blrow + pc * 32 + quad * 8);
        c = MFMA16(ah, bh, c);
        c = MFMA16(ah, bl, c);
        c = MFMA16(al, bh, c);
    }
    // lane holds K[i = m*64+ht*16+n][e = quad*4+r], r=0..3
    int i = m * 64 + ht * 16 + n;
    size_t bK = (size_t)b * 2112;
    size_t bT = (size_t)b * 33792;
    u16 h[4], l[4];
#pragma unroll
    for (int r = 0; r < 4; ++r) {
        h[r] = bf16rn(c[r]);
        l[r] = bf16rn(c[r] - bf16tof(h[r]));
    }
    *(uint2*)(Kh + (bK + i) * 16 + quad * 4) =
        make_uint2((unsigned)h[0] | ((unsigned)h[1] << 16), (unsigned)h[2] | ((unsigned)h[3] << 16));
    *(uint2*)(Kl + (bK + i) * 16 + quad * 4) =
        make_uint2((unsigned)l[0] | ((unsigned)l[1] << 16), (unsigned)l[2] | ((unsigned)l[3] << 16));
#pragma unroll
    for (int r = 0; r < 4; ++r) {
        KhT[bT + (size_t)(quad * 4 + r) * 2112 + i] = h[r];
        KlT[bT + (size_t)(quad * 4 + r) * 2112 + i] = l[r];
    }
}

// ---------------------------------------------------------------------------
// Q conversion (x0.25, hi/lo) + rel rows into K arrays (i 2048..2111, pad->0).
__global__ __launch_bounds__(256) void k_cvt(const float* __restrict__ qconv,
                                             const float* __restrict__ rel,
                                             u16* __restrict__ Qp,
                                             u16* __restrict__ Kh,
                                             u16* __restrict__ Kl,
                                             u16* __restrict__ KhT,
                                             u16* __restrict__ KlT) {
    int blk = blockIdx.x, tid = threadIdx.x;
    if (blk < 196) {                        // Q rows [0, 50176)
        int gid = blk * 256 + tid;
        const float4* q4 = (const float4*)(qconv + (size_t)gid * 16);
        float4 t0 = q4[0], t1 = q4[1], t2 = q4[2], t3 = q4[3];
        float v[16] = {t0.x,t0.y,t0.z,t0.w, t1.x,t1.y,t1.z,t1.w,
                       t2.x,t2.y,t2.z,t2.w, t3.x,t3.y,t3.z,t3.w};
        unsigned hw[8], lw[8];
#pragma unroll
        for (int t = 0; t < 8; ++t) {
            float x0 = v[2*t] * 0.25f, x1 = v[2*t+1] * 0.25f;
            u16 h0 = bf16rn(x0), h1 = bf16rn(x1);
            u16 l0 = bf16rn(x0 - bf16tof(h0)), l1 = bf16rn(x1 - bf16tof(h1));
            hw[t] = (unsigned)h0 | ((unsigned)h1 << 16);
            lw[t] = (unsigned)l0 | ((unsigned)l1 << 16);
        }
        uint4* r4 = (uint4*)(Qp + (size_t)gid * 32);
        r4[0] = make_uint4(hw[0], hw[1], hw[2], hw[3]);
        r4[1] = make_uint4(hw[4], hw[5], hw[6], hw[7]);
        r4[2] = make_uint4(lw[0], lw[1], lw[2], lw[3]);
        r4[3] = make_uint4(lw[4], lw[5], lw[6], lw[7]);
    } else {                                // rel rows: one block per batch
        int b = blk - 196;
        size_t bK = (size_t)b * 2112;
        size_t bT = (size_t)b * 33792;
#pragma unroll
        for (int k = 0; k < 4; ++k) {
            int idx = tid + k * 256;        // [0,1024)
            int row = idx >> 4, e = idx & 15;
            int i = 2048 + row;
            float v = (row < 49) ? rel[e * 49 + row] : 0.f;
            u16 h = bf16rn(v);
            u16 l = bf16rn(v - bf16tof(h));
            Kh[(bK + i) * 16 + e] = h;
            Kl[(bK + i) * 16 + e] = l;
            KhT[bT + (size_t)e * 2112 + i] = h;
            KlT[bT + (size_t)e * 2112 + i] = l;
        }
    }
}

// ---------------------------------------------------------------------------
// Column denominators: barrier-free, K frags in registers, Q streamed from L2.
// dpart[jh][b][2112] = sum_{j in half} exp(S[j,i])
__global__ __launch_bounds__(256) void k_stats4(const u16* __restrict__ Qp,
                                                const u16* __restrict__ Kh,
                                                const u16* __restrict__ Kl,
                                                float* __restrict__ dpart) {
    int blk = blockIdx.x;                   // b*34 + jh*17 + tb
    int b = blk / 34; int rem = blk % 34; int jh = rem / 17; int tb = rem % 17;
    int wave = threadIdx.x >> 6, lane = threadIdx.x & 63;
    int it2 = tb * 4 + wave;                // i-pair 0..67
    if (it2 >= 66) return;
    int ibase = it2 * 32;
    int n = lane & 15, quad = lane >> 4;
    size_t bK = (size_t)b * 2112;
    const u16* kb = Kh + (bK + ibase + n) * 16 + (quad & 1) * 8;
    const u16* lb = Kl + (bK + ibase + n) * 16 + (quad & 1) * 8;
    short8 bh0 = ld8(kb), bh1 = ld8(kb + 256);
    short8 bl0 = ld8(lb), bl1 = ld8(lb + 256);
    const u16* qb = Qp + (size_t)b * 50176 + (size_t)jh * 49 * 512 + n * 32 + quad * 8;
    floatx4 d0 = {0.f,0.f,0.f,0.f}, d1 = {0.f,0.f,0.f,0.f};
    short8 a0 = ld8(qb), a1 = ld8(qb + 512);
    for (int c = 0; c < 49; ++c) {
        short8 a2 = (c + 2 < 49) ? ld8(qb + (size_t)(c + 2) * 512) : a0;
        floatx4 s0 = {0.f,0.f,0.f,0.f}, s1 = {0.f,0.f,0.f,0.f};
        s0 = MFMA16(a0, bh0, s0);
        s0 = MFMA16(a0, bl0, s0);
        s1 = MFMA16(a0, bh1, s1);
        s1 = MFMA16(a0, bl1, s1);
        d0.x += __expf(s0.x); d0.y += __expf(s0.y);
        d0.z += __expf(s0.z); d0.w += __expf(s0.w);
        d1.x += __expf(s1.x); d1.y += __expf(s1.y);
        d1.z += __expf(s1.z); d1.w += __expf(s1.w);
        a0 = a1; a1 = a2;
    }
    float t0 = d0.x + d0.y + d0.z + d0.w;
    float t1 = d1.x + d1.y + d1.z + d1.w;
    t0 += __shfl_xor(t0, 16); t0 += __shfl_xor(t0, 32);
    t1 += __shfl_xor(t1, 16); t1 += __shfl_xor(t1, 32);
    if (quad == 0) {
        dpart[(size_t)jh * 67584 + bK + ibase + n]      = t0;
        dpart[(size_t)jh * 67584 + bK + ibase + 16 + n] = t1;
    }
}

// ---------------------------------------------------------------------------
// PV: conflict-clean lane-ordered LDS staging, packed-u32 W transpose, i-split x2.
__global__ __launch_bounds__(256) void k_pv4(const u16* __restrict__ Qp,
                                             const u16* __restrict__ Kh,
                                             const u16* __restrict__ Kl,
                                             const u16* __restrict__ KhT,
                                             const u16* __restrict__ KlT,
                                             const float* __restrict__ dpart,
                                             float* __restrict__ opart) {
    __shared__ __align__(16) u16 sH[2][32][2][8];     // [buf][i][ehalf][8] 2KB
    __shared__ __align__(16) u16 sL[2][32][2][8];
    __shared__ __align__(16) u16 tH[2][16][32];       // [buf][e][i-local] 2KB
    __shared__ __align__(16) u16 tL[2][16][32];
    __shared__ __align__(16) unsigned wbuf[4][16][36];// per-wave W (hi|lo) u32
    __shared__ float rll[2][32];

    int blk = blockIdx.x;                  // b*50 + jtb*2 + ih
    int b = blk / 50; int rem = blk % 50; int jtb = rem >> 1; int ih = rem & 1;
    int tid = threadIdx.x, wave = tid >> 6, lane = tid & 63;
    int n = lane & 15, quad = lane >> 4, qh = quad & 1;
    int jt = jtb * 4 + wave;
    int jtc = jt < 98 ? jt : 97;
    int i0 = ih * 1056;
    size_t bK = (size_t)b * 2112;
    size_t bT = (size_t)b * 33792;
    const float* d0p = dpart + bK;
    const float* d1p = dpart + 67584 + bK;

    short8 aq = ld8(Qp + ((size_t)b * 1568 + (size_t)jtc * 16 + n) * 32 + quad * 8);

    int role = wave, L = lane;
    uint4 sreg; float dv = 1.f;
    auto ldchunk = [&](int c) {
        int i0c = i0 + c * 32;
        if (role == 0)      sreg = *(const uint4*)(Kh  + (bK + i0c + (L >> 1)) * 16 + (L & 1) * 8);
        else if (role == 1) sreg = *(const uint4*)(Kl  + (bK + i0c + (L >> 1)) * 16 + (L & 1) * 8);
        else if (role == 2) sreg = *(const uint4*)(KhT + bT + (size_t)(L >> 2) * 2112 + i0c + (L & 3) * 8);
        else {
            sreg = *(const uint4*)(KlT + bT + (size_t)(L >> 2) * 2112 + i0c + (L & 3) * 8);
            if (L < 32) dv = d0p[i0c + L] + d1p[i0c + L];
        }
    };
    auto stchunk = [&](int bf) {
        if (role == 0)      *(uint4*)(&sH[bf][L >> 1][L & 1][0]) = sreg;
        else if (role == 1) *(uint4*)(&sL[bf][L >> 1][L & 1][0]) = sreg;
        else if (role == 2) *(uint4*)(&tH[bf][L >> 2][(L & 3) * 8]) = sreg;
        else {
            *(uint4*)(&tL[bf][L >> 2][(L & 3) * 8]) = sreg;
            if (L < 32) rll[bf][L] = 1.0f / dv;
        }
    };

    floatx4 o = {0.f, 0.f, 0.f, 0.f};

    ldchunk(0); stchunk(0); ldchunk(1);
    __syncthreads();
    for (int c = 0; c < 33; ++c) {
        int cb = c & 1;
        short8 sh0 = ld8(&sH[cb][n][qh][0]);
        short8 sh1 = ld8(&sH[cb][16 + n][qh][0]);
        short8 sl0 = ld8(&sL[cb][n][qh][0]);
        short8 sl1 = ld8(&sL[cb][16 + n][qh][0]);
        short8 th  = ld8(&tH[cb][n][quad * 8]);
        short8 tl  = ld8(&tL[cb][n][quad * 8]);
        float r0 = rll[cb][n], r1 = rll[cb][16 + n];
        floatx4 s0 = {0.f,0.f,0.f,0.f};
        s0 = MFMA16(aq, sh0, s0);
        s0 = MFMA16(aq, sl0, s0);
        floatx4 s1 = {0.f,0.f,0.f,0.f};
        s1 = MFMA16(aq, sh1, s1);
        s1 = MFMA16(aq, sl1, s1);
#pragma unroll
        for (int r = 0; r < 4; ++r) {
            float w0 = __expf(s0[r]) * r0;
            float w1 = __expf(s1[r]) * r1;
            unsigned u0 = __float_as_uint(w0), u1 = __float_as_uint(w1);
            unsigned h0 = u0 & 0xffff0000u, h1 = u1 & 0xffff0000u;
            float l0 = w0 - __uint_as_float(h0);
            float l1 = w1 - __uint_as_float(h1);
            wbuf[wave][quad * 4 + r][n]      = h0 | (__float_as_uint(l0) >> 16);
            wbuf[wave][quad * 4 + r][16 + n] = h1 | (__float_as_uint(l1) >> 16);
        }
        asm volatile("s_waitcnt lgkmcnt(0)" ::: "memory");
        uint4 wa = *(const uint4*)(&wbuf[wave][n][quad * 8]);
        uint4 wb = *(const uint4*)(&wbuf[wave][n][quad * 8 + 4]);
        union { unsigned u[4]; short8 s; } hv, lv;
        hv.u[0] = (wa.x >> 16) | (wa.y & 0xffff0000u);
        hv.u[1] = (wa.z >> 16) | (wa.w & 0xffff0000u);
        hv.u[2] = (wb.x >> 16) | (wb.y & 0xffff0000u);
        hv.u[3] = (wb.z >> 16) | (wb.w & 0xffff0000u);
        lv.u[0] = (wa.x & 0xffffu) | (wa.y << 16);
        lv.u[1] = (wa.z & 0xffffu) | (wa.w << 16);
        lv.u[2] = (wb.x & 0xffffu) | (wb.y << 16);
        lv.u[3] = (wb.z & 0xffffu) | (wb.w << 16);
        o = MFMA16(hv.s, th, o);
        o = MFMA16(hv.s, tl, o);
        o = MFMA16(lv.s, th, o);
        if (c < 32) stchunk((c + 1) & 1);
        if (c < 31) ldchunk(c + 2);
        __syncthreads();
    }
    if (jt < 98) {
        float* ob = opart + (size_t)ih * 802816 + ((size_t)b * 1568 + (size_t)jt * 16) * 16;
#pragma unroll
        for (int r = 0; r < 4; ++r) ob[(quad * 4 + r) * 16 + n] = o[r];
    }
}

// ---------------------------------------------------------------------------
// LayerNorm over consecutive groups of 16 floats.
__global__ __launch_bounds__(256) void k_ln(const float* __restrict__ x,
                                            const float* __restrict__ gamma,
                                            const float* __restrict__ beta,
                                            float* __restrict__ out, int ngroups) {
    int g = blockIdx.x * 256 + threadIdx.x;
    if (g >= ngroups) return;
    const float4* xp = (const float4*)(x + (size_t)g * 16);
    float4 x0 = xp[0], x1 = xp[1], x2 = xp[2], x3 = xp[3];
    float sum = x0.x + x0.y + x0.z + x0.w + x1.x + x1.y + x1.z + x1.w
              + x2.x + x2.y + x2.z + x2.w + x3.x + x3.y + x3.z + x3.w;
    float mu = sum * 0.0625f;
    float var = 0.f;
    var += (x0.x-mu)*(x0.x-mu) + (x0.y-mu)*(x0.y-mu) + (x0.z-mu)*(x0.z-mu) + (x0.w-mu)*(x0.w-mu);
    var += (x1.x-mu)*(x1.x-mu) + (x1.y-mu)*(x1.y-mu) + (x1.z-mu)*(x1.z-mu) + (x1.w-mu)*(x1.w-mu);
    var += (x2.x-mu)*(x2.x-mu) + (x2.y-mu)*(x2.y-mu) + (x2.z-mu)*(x2.z-mu) + (x2.w-mu)*(x2.w-mu);
    var += (x3.x-mu)*(x3.x-mu) + (x3.y-mu)*(x3.y-mu) + (x3.z-mu)*(x3.z-mu) + (x3.w-mu)*(x3.w-mu);
    float rstd = rsqrtf(var * 0.0625f + 1e-5f);
    const float4* gp = (const float4*)gamma;
    const float4* bp = (const float4*)beta;
    float4 g0 = gp[0], g1 = gp[1], g2 = gp[2], g3 = gp[3];
    float4 be0 = bp[0], be1 = bp[1], be2 = bp[2], be3 = bp[3];
    float4 o0, o1, o2, o3;
    o0.x = (x0.x-mu)*rstd*g0.x + be0.x; o0.y = (x0.y-mu)*rstd*g0.y + be0.y;
    o0.z = (x0.z-mu)*rstd*g0.z + be0.z; o0.w = (x0.w-mu)*rstd*g0.w + be0.w;
    o1.x = (x1.x-mu)*rstd*g1.x + be1.x; o1.y = (x1.y-mu)*rstd*g1.y + be1.y;
    o1.z = (x1.z-mu)*rstd*g1.z + be1.z; o1.w = (x1.w-mu)*rstd*g1.w + be1.w;
    o2.x = (x2.x-mu)*rstd*g2.x + be2.x; o2.y = (x2.y-mu)*rstd*g2.y + be2.y;
    o2.z = (x2.z-mu)*rstd*g2.z + be2.z; o2.w = (x2.w-mu)*rstd*g2.w + be2.w;
    o3.x = (x3.x-mu)*rstd*g3.x + be3.x; o3.y = (x3.y-mu)*rstd*g3.y + be3.y;
    o3.z = (x3.z-mu)*rstd*g3.z + be3.z; o3.w = (x3.w-mu)*rstd*g3.w + be3.w;
    float4* op = (float4*)(out + (size_t)g * 16);
    op[0] = o0; op[1] = o1; op[2] = o2; op[3] = o3;
}

// ---------------------------------------------------------------------------
extern "C" void kernel_launch(void* const* d_in, const int* in_sizes, int n_in,
                              void* d_out, int out_size, void* d_ws, size_t ws_size,
                              hipStream_t stream) {
    const float* current_pose = (const float*)d_in[0];
    const float* next_pose    = (const float*)d_in[1];
    const float* current_w    = (const float*)d_in[2];
    const float* next_w       = (const float*)d_in[3];
    const float* E_proj       = (const float*)d_in[4];
    const float* rel          = (const float*)d_in[5];
    const float* ln_gamma     = (const float*)d_in[6];
    const float* ln_beta      = (const float*)d_in[7];
    float* out = (float*)d_out;
    float* ws  = (float*)d_ws;

    // workspace (floats); cpconv region reused by opart/dpart/conv2 after kproj2
    float* cpconv = ws;                 // 3,211,264
    float* conv2  = ws;                 // alias (written after cpconv last read)
    float* opart  = ws + 802816;        // 2 x 802,816 -> ends 2,408,448
    float* dpart  = ws + 2408448;       // 2 x 67,584 -> ends 2,543,616
    float* qconv  = ws + 3211264;       //   802,816
    u16*   ub     = (u16*)(ws + 4014080);
    u16* Qp  = ub;                      // 1,605,632
    u16* Kh  = ub + 1605632;            // 1,081,344
    u16* Kl  = ub + 2686976;
    u16* KhT = ub + 3768320;
    u16* KlT = ub + 4849664;
    u16* EhT = ub + 5931008;            // 458,752
    u16* ElT = ub + 6389760;            // ends 6,848,512 (~29.8 MB total)

    k_conv14<<<1024, 256, 0, stream>>>(current_pose, current_w, cpconv);
    k_conv7 <<<2048, 64,  0, stream>>>(next_pose, next_pose, next_w, qconv, 1);
    k_ecvt  <<<32,   256, 0, stream>>>(E_proj, EhT, ElT);
    k_cvt   <<<228,  256, 0, stream>>>(qconv, rel, Qp, Kh, Kl, KhT, KlT);
    k_kproj2<<<1024, 256, 0, stream>>>(cpconv, EhT, ElT, Kh, Kl, KhT, KlT);
    k_stats4<<<1088, 256, 0, stream>>>(Qp, Kh, Kl, dpart);
    k_pv4   <<<1600, 256, 0, stream>>>(Qp, Kh, Kl, KhT, KlT, dpart, opart);
    k_conv7 <<<2048, 64,  0, stream>>>(opart, opart + 802816, next_w, conv2, 0);
    k_ln    <<<196,  256, 0, stream>>>(conv2, ln_gamma, ln_beta, out, 50176);
}

// Round 5
// 232.323 us; speedup vs baseline: 2.2362x; 1.0544x over previous
//
#include <hip/hip_runtime.h>

typedef unsigned short u16;
typedef __attribute__((ext_vector_type(8))) short short8;   // 8 bf16 = 4 VGPRs
typedef __attribute__((ext_vector_type(4))) float floatx4;

#define MFMA16(a, b, c) __builtin_amdgcn_mfma_f32_16x16x32_bf16(a, b, c, 0, 0, 0)

__device__ inline u16 bf16rn(float x) {
    unsigned u = __float_as_uint(x);
    u += 0x7fffu + ((u >> 16) & 1u);
    return (u16)(u >> 16);
}
__device__ inline float bf16tof(u16 h) { return __uint_as_float(((unsigned)h) << 16); }
__device__ inline short8 ld8(const u16* p) { return *(const short8*)p; }

// ---------------------------------------------------------------------------
// Consolidated precompute: E transpose (blk<32), rel K rows (blk 32..63),
// conv14 weight transpose w2[g][ic][oc*9+kk] (blk 64..71).
__global__ __launch_bounds__(256) void k_ecvt2(const float* __restrict__ E,
                                               const float* __restrict__ rel,
                                               const float* __restrict__ w,
                                               u16* __restrict__ EhT,
                                               u16* __restrict__ ElT,
                                               u16* __restrict__ Kh,
                                               u16* __restrict__ Kl,
                                               u16* __restrict__ KhT,
                                               u16* __restrict__ KlT,
                                               float* __restrict__ w2) {
    int blk = blockIdx.x, tid = threadIdx.x;
    if (blk < 32) {                       // E transpose + hi/lo
        __shared__ float ep[196 * 65];
        int m = blk;
        const float* eb = E + (size_t)m * 12544;
        for (int t = tid; t < 12544; t += 256) {
            int p = t >> 6, h = t & 63;
            ep[p * 65 + h] = eb[t];
        }
        __syncthreads();
        for (int t = tid; t < 64 * 224; t += 256) {
            int h = t / 224, p = t % 224;
            float v = (p < 196) ? ep[p * 65 + h] : 0.f;
            u16 hi = bf16rn(v);
            u16 lo = bf16rn(v - bf16tof(hi));
            EhT[(size_t)m * 14336 + t] = hi;
            ElT[(size_t)m * 14336 + t] = lo;
        }
    } else if (blk < 64) {                // rel rows -> K arrays (i 2048..2111)
        int b = blk - 32;
        size_t bK = (size_t)b * 2112;
        size_t bT = (size_t)b * 33792;
#pragma unroll
        for (int k = 0; k < 4; ++k) {
            int idx = tid + k * 256;      // [0,1024)
            int row = idx >> 4, e = idx & 15;
            int i = 2048 + row;
            float v = (row < 49) ? rel[e * 49 + row] : 0.f;
            u16 h = bf16rn(v);
            u16 l = bf16rn(v - bf16tof(h));
            Kh[(bK + i) * 16 + e] = h;
            Kl[(bK + i) * 16 + e] = l;
            KhT[bT + (size_t)e * 2112 + i] = h;
            KlT[bT + (size_t)e * 2112 + i] = l;
        }
    } else {                              // conv14 weight transpose, 4 g per block
        int g0 = (blk - 64) * 4;
        for (int t = tid; t < 4 * 2304; t += 256) {
            int g = g0 + t / 2304, r = t % 2304;
            int oc = r / 144, rr = r % 144;
            w2[(size_t)g * 2304 + (rr / 9) * 144 + oc * 9 + (rr % 9)] =
                w[(size_t)g * 2304 + r];
        }
    }
}

// ---------------------------------------------------------------------------
// Grouped 3x3 conv 14x14, oc-split x2, transposed weights (contiguous s_load).
__global__ __launch_bounds__(256) void k_conv14(const float* __restrict__ pose,
                                                const float* __restrict__ w2,
                                                float* __restrict__ out) {
    int blk = blockIdx.x;          // (b*32+g)*2 + oh
    int oh = blk & 1, bg = blk >> 1;
    int tid = threadIdx.x;
    __shared__ float patch[16 * 256];
#pragma unroll
    for (int k = 0; k < 16; ++k) patch[k * 256 + tid] = 0.f;
    __syncthreads();
    const float* pin = pose + (size_t)bg * 3136;
    for (int t = tid; t < 3136; t += 256) {
        int p = t >> 4, ic = t & 15;
        int y = p / 14, x = p % 14;
        patch[ic * 256 + (y + 1) * 16 + (x + 1)] = pin[t];
    }
    __syncthreads();
    int g = bg & 31;
    const float* wg = w2 + (size_t)g * 2304 + oh * 72;
    float* po = out + (size_t)bg * 3136 + oh * 8 * 196;
    if (tid < 196) {
        int y = tid / 14, x = tid % 14;
        int base = (y + 1) * 16 + (x + 1);
        float acc[8];
#pragma unroll
        for (int oc = 0; oc < 8; ++oc) acc[oc] = 0.f;
        for (int ic = 0; ic < 16; ++ic) {
            const float* pr = patch + ic * 256 + base;
            float win[9];
#pragma unroll
            for (int ky = 0; ky < 3; ++ky)
#pragma unroll
                for (int kx = 0; kx < 3; ++kx)
                    win[ky * 3 + kx] = pr[(ky - 1) * 16 + (kx - 1)];
            const float* wi = wg + ic * 144;
#pragma unroll
            for (int oc = 0; oc < 8; ++oc)
#pragma unroll
                for (int kk = 0; kk < 9; ++kk)
                    acc[oc] += win[kk] * wi[oc * 9 + kk];
        }
#pragma unroll
        for (int oc = 0; oc < 8; ++oc) po[oc * 196 + tid] = acc[oc];
    }
}

// ---------------------------------------------------------------------------
// Grouped 3x3 conv 7x7, oc-split x2. mode=1: permuted pose input; mode=0: in+in2.
__global__ __launch_bounds__(64) void k_conv7(const float* __restrict__ in,
                                              const float* __restrict__ in2,
                                              const float* __restrict__ w,
                                              float* __restrict__ out, int mode) {
    int blk = blockIdx.x;          // (b*32+g)*2 + oh
    int oh = blk & 1, bg = blk >> 1;
    int tid = threadIdx.x;
    __shared__ float patch[16 * 144];
    for (int t = tid; t < 16 * 144; t += 64) patch[t] = 0.f;
    __syncthreads();
    const float* pin = in + (size_t)bg * 784;
    if (mode == 1) {
        for (int t = tid; t < 784; t += 64) {
            int p = t >> 4, ic = t & 15;
            int y = p / 7, x = p % 7;
            patch[ic * 144 + (y + 1) * 16 + (x + 1)] = pin[t];
        }
    } else {
        const float* pin2 = in2 + (size_t)bg * 784;
        for (int t = tid; t < 784; t += 64) {
            int ic = t / 49, p = t % 49;
            int y = p / 7, x = p % 7;
            patch[ic * 144 + (y + 1) * 16 + (x + 1)] = pin[t] + pin2[t];
        }
    }
    __syncthreads();
    int g = bg & 31;
    const float* wg = w + (size_t)g * 2304 + (size_t)oh * 8 * 144;
    float* po = out + (size_t)bg * 784 + (size_t)oh * 8 * 49;
    if (tid < 49) {
        int y = tid / 7, x = tid % 7;
        int base = (y + 1) * 16 + (x + 1);
        float acc[8];
#pragma unroll
        for (int oc = 0; oc < 8; ++oc) acc[oc] = 0.f;
        for (int ic = 0; ic < 16; ++ic) {
            const float* pr = patch + ic * 144 + base;
            float win[9];
#pragma unroll
            for (int ky = 0; ky < 3; ++ky)
#pragma unroll
                for (int kx = 0; kx < 3; ++kx)
                    win[ky * 3 + kx] = pr[(ky - 1) * 16 + (kx - 1)];
            const float* wi = wg + ic * 9;
#pragma unroll
            for (int oc = 0; oc < 8; ++oc)
#pragma unroll
                for (int kk = 0; kk < 9; ++kk)
                    acc[oc] += win[kk] * wi[oc * 144 + kk];
        }
#pragma unroll
        for (int oc = 0; oc < 8; ++oc) po[oc * 49 + tid] = acc[oc];
    }
}

// ---------------------------------------------------------------------------
// MFMA key projection: per (b,m): D[16e x 64h] = cp[16e x 196p] * E[m][196p x 64h].
__global__ __launch_bounds__(256) void k_kproj2(const float* __restrict__ cpconv,
                                                const u16* __restrict__ EhT,
                                                const u16* __restrict__ ElT,
                                                u16* __restrict__ Kh,
                                                u16* __restrict__ Kl,
                                                u16* __restrict__ KhT,
                                                u16* __restrict__ KlT) {
    int blk = blockIdx.x;           // b*32 + m
    int b = blk >> 5, m = blk & 31;
    int wave = threadIdx.x >> 6, lane = threadIdx.x & 63;
    int ht = wave;                  // h-tile 0..3
    int n = lane & 15, quad = lane >> 4;

    const float* arow = cpconv + ((size_t)b * 512 + (size_t)n * 32 + m) * 196;
    const u16* bhrow = EhT + ((size_t)m * 64 + ht * 16 + n) * 224;
    const u16* blrow = ElT + ((size_t)m * 64 + ht * 16 + n) * 224;

    floatx4 c = {0.f, 0.f, 0.f, 0.f};
#pragma unroll
    for (int pc = 0; pc < 7; ++pc) {
        int p0 = pc * 32 + quad * 8;
        float av[8];
        if (p0 <= 188) {
            float4 x = *(const float4*)(arow + p0);
            float4 y = *(const float4*)(arow + p0 + 4);
            av[0]=x.x; av[1]=x.y; av[2]=x.z; av[3]=x.w;
            av[4]=y.x; av[5]=y.y; av[6]=y.z; av[7]=y.w;
        } else {
#pragma unroll
            for (int k2 = 0; k2 < 8; ++k2) av[k2] = (p0 + k2 < 196) ? arow[p0 + k2] : 0.f;
        }
        short8 ah, al;
#pragma unroll
        for (int k2 = 0; k2 < 8; ++k2) {
            u16 h = bf16rn(av[k2]);
            ah[k2] = (short)h;
            al[k2] = (short)bf16rn(av[k2] - bf16tof(h));
        }
        short8 bh = ld8(bhrow + pc * 32 + quad * 8);
        short8 bl = ld8(blrow + pc * 32 + quad * 8);
        c = MFMA16(ah, bh, c);
        c = MFMA16(ah, bl, c);
        c = MFMA16(al, bh, c);
    }
    int i = m * 64 + ht * 16 + n;
    size_t bK = (size_t)b * 2112;
    size_t bT = (size_t)b * 33792;
    u16 h[4], l[4];
#pragma unroll
    for (int r = 0; r < 4; ++r) {
        h[r] = bf16rn(c[r]);
        l[r] = bf16rn(c[r] - bf16tof(h[r]));
    }
    *(uint2*)(Kh + (bK + i) * 16 + quad * 4) =
        make_uint2((unsigned)h[0] | ((unsigned)h[1] << 16), (unsigned)h[2] | ((unsigned)h[3] << 16));
    *(uint2*)(Kl + (bK + i) * 16 + quad * 4) =
        make_uint2((unsigned)l[0] | ((unsigned)l[1] << 16), (unsigned)l[2] | ((unsigned)l[3] << 16));
#pragma unroll
    for (int r = 0; r < 4; ++r) {
        KhT[bT + (size_t)(quad * 4 + r) * 2112 + i] = h[r];
        KlT[bT + (size_t)(quad * 4 + r) * 2112 + i] = l[r];
    }
}

// ---------------------------------------------------------------------------
// Q conversion (x0.25, hi/lo bf16).
__global__ __launch_bounds__(256) void k_cvt(const float* __restrict__ qconv,
                                             u16* __restrict__ Qp) {
    int gid = blockIdx.x * 256 + threadIdx.x;
    const float4* q4 = (const float4*)(qconv + (size_t)gid * 16);
    float4 t0 = q4[0], t1 = q4[1], t2 = q4[2], t3 = q4[3];
    float v[16] = {t0.x,t0.y,t0.z,t0.w, t1.x,t1.y,t1.z,t1.w,
                   t2.x,t2.y,t2.z,t2.w, t3.x,t3.y,t3.z,t3.w};
    unsigned hw[8], lw[8];
#pragma unroll
    for (int t = 0; t < 8; ++t) {
        float x0 = v[2*t] * 0.25f, x1 = v[2*t+1] * 0.25f;
        u16 h0 = bf16rn(x0), h1 = bf16rn(x1);
        u16 l0 = bf16rn(x0 - bf16tof(h0)), l1 = bf16rn(x1 - bf16tof(h1));
        hw[t] = (unsigned)h0 | ((unsigned)h1 << 16);
        lw[t] = (unsigned)l0 | ((unsigned)l1 << 16);
    }
    uint4* r4 = (uint4*)(Qp + (size_t)gid * 32);
    r4[0] = make_uint4(hw[0], hw[1], hw[2], hw[3]);
    r4[1] = make_uint4(hw[4], hw[5], hw[6], hw[7]);
    r4[2] = make_uint4(lw[0], lw[1], lw[2], lw[3]);
    r4[3] = make_uint4(lw[4], lw[5], lw[6], lw[7]);
}

// ---------------------------------------------------------------------------
// Column denominators: barrier-free, K frags in registers, Q streamed from L2.
__global__ __launch_bounds__(256) void k_stats4(const u16* __restrict__ Qp,
                                                const u16* __restrict__ Kh,
                                                const u16* __restrict__ Kl,
                                                float* __restrict__ dpart) {
    int blk = blockIdx.x;                   // b*34 + jh*17 + tb
    int b = blk / 34; int rem = blk % 34; int jh = rem / 17; int tb = rem % 17;
    int wave = threadIdx.x >> 6, lane = threadIdx.x & 63;
    int it2 = tb * 4 + wave;                // i-pair 0..67
    if (it2 >= 66) return;
    int ibase = it2 * 32;
    int n = lane & 15, quad = lane >> 4;
    size_t bK = (size_t)b * 2112;
    const u16* kb = Kh + (bK + ibase + n) * 16 + (quad & 1) * 8;
    const u16* lb = Kl + (bK + ibase + n) * 16 + (quad & 1) * 8;
    short8 bh0 = ld8(kb), bh1 = ld8(kb + 256);
    short8 bl0 = ld8(lb), bl1 = ld8(lb + 256);
    const u16* qb = Qp + (size_t)b * 50176 + (size_t)jh * 49 * 512 + n * 32 + quad * 8;
    floatx4 d0 = {0.f,0.f,0.f,0.f}, d1 = {0.f,0.f,0.f,0.f};
    short8 a0 = ld8(qb), a1 = ld8(qb + 512);
    for (int c = 0; c < 49; ++c) {
        short8 a2 = (c + 2 < 49) ? ld8(qb + (size_t)(c + 2) * 512) : a0;
        floatx4 s0 = {0.f,0.f,0.f,0.f}, s1 = {0.f,0.f,0.f,0.f};
        s0 = MFMA16(a0, bh0, s0);
        s0 = MFMA16(a0, bl0, s0);
        s1 = MFMA16(a0, bh1, s1);
        s1 = MFMA16(a0, bl1, s1);
        d0.x += __expf(s0.x); d0.y += __expf(s0.y);
        d0.z += __expf(s0.z); d0.w += __expf(s0.w);
        d1.x += __expf(s1.x); d1.y += __expf(s1.y);
        d1.z += __expf(s1.z); d1.w += __expf(s1.w);
        a0 = a1; a1 = a2;
    }
    float t0 = d0.x + d0.y + d0.z + d0.w;
    float t1 = d1.x + d1.y + d1.z + d1.w;
    t0 += __shfl_xor(t0, 16); t0 += __shfl_xor(t0, 32);
    t1 += __shfl_xor(t1, 16); t1 += __shfl_xor(t1, 32);
    if (quad == 0) {
        dpart[(size_t)jh * 67584 + bK + ibase + n]      = t0;
        dpart[(size_t)jh * 67584 + bK + ibase + 16 + n] = t1;
    }
}

// ---------------------------------------------------------------------------
// PV: bf16-truncated W (no lo term), minimal LDS round-trip, i-split x2.
__global__ __launch_bounds__(256) void k_pv5(const u16* __restrict__ Qp,
                                             const u16* __restrict__ Kh,
                                             const u16* __restrict__ Kl,
                                             const u16* __restrict__ KhT,
                                             const u16* __restrict__ KlT,
                                             const float* __restrict__ dpart,
                                             float* __restrict__ opart) {
    __shared__ __align__(16) u16 sH[2][32][16];       // [buf][i][e]
    __shared__ __align__(16) u16 sL[2][32][16];
    __shared__ __align__(16) u16 tH[2][16][32];       // [buf][e][i-local]
    __shared__ __align__(16) u16 tL[2][16][32];
    __shared__ __align__(16) u16 w16[4][16][40];      // per-wave W bf16, stride 40
    __shared__ float rll[2][32];

    int blk = blockIdx.x;                  // b*50 + jtb*2 + ih
    int b = blk / 50; int rem = blk % 50; int jtb = rem >> 1; int ih = rem & 1;
    int tid = threadIdx.x, wave = tid >> 6, lane = tid & 63;
    int n = lane & 15, quad = lane >> 4, qh = quad & 1;
    int jt = jtb * 4 + wave;
    int jtc = jt < 98 ? jt : 97;
    int i0 = ih * 1056;
    size_t bK = (size_t)b * 2112;
    size_t bT = (size_t)b * 33792;
    const float* d0p = dpart + bK;
    const float* d1p = dpart + 67584 + bK;

    short8 aq = ld8(Qp + ((size_t)b * 1568 + (size_t)jtc * 16 + n) * 32 + quad * 8);

    int role = wave, L = lane;
    uint4 sreg; float dv = 1.f;
    auto ldchunk = [&](int c) {
        int i0c = i0 + c * 32;
        if (role == 0)      sreg = *(const uint4*)(Kh  + (bK + i0c + (L >> 1)) * 16 + (L & 1) * 8);
        else if (role == 1) sreg = *(const uint4*)(Kl  + (bK + i0c + (L >> 1)) * 16 + (L & 1) * 8);
        else if (role == 2) sreg = *(const uint4*)(KhT + bT + (size_t)(L >> 2) * 2112 + i0c + (L & 3) * 8);
        else {
            sreg = *(const uint4*)(KlT + bT + (size_t)(L >> 2) * 2112 + i0c + (L & 3) * 8);
            if (L < 32) dv = d0p[i0c + L] + d1p[i0c + L];
        }
    };
    auto stchunk = [&](int bf) {
        if (role == 0)      *(uint4*)(&sH[bf][L >> 1][(L & 1) * 8]) = sreg;
        else if (role == 1) *(uint4*)(&sL[bf][L >> 1][(L & 1) * 8]) = sreg;
        else if (role == 2) *(uint4*)(&tH[bf][L >> 2][(L & 3) * 8]) = sreg;
        else {
            *(uint4*)(&tL[bf][L >> 2][(L & 3) * 8]) = sreg;
            if (L < 32) rll[bf][L] = 1.0f / dv;
        }
    };

    floatx4 o = {0.f, 0.f, 0.f, 0.f};

    ldchunk(0); stchunk(0); ldchunk(1);
    __syncthreads();
    for (int c = 0; c < 33; ++c) {
        int cb = c & 1;
        short8 sh0 = ld8(&sH[cb][n][qh * 8]);
        short8 sh1 = ld8(&sH[cb][16 + n][qh * 8]);
        short8 sl0 = ld8(&sL[cb][n][qh * 8]);
        short8 sl1 = ld8(&sL[cb][16 + n][qh * 8]);
        short8 th  = ld8(&tH[cb][n][quad * 8]);
        short8 tl  = ld8(&tL[cb][n][quad * 8]);
        float r0 = rll[cb][n], r1 = rll[cb][16 + n];
        floatx4 s0 = {0.f,0.f,0.f,0.f};
        s0 = MFMA16(aq, sh0, s0);
        s0 = MFMA16(aq, sl0, s0);
        floatx4 s1 = {0.f,0.f,0.f,0.f};
        s1 = MFMA16(aq, sh1, s1);
        s1 = MFMA16(aq, sl1, s1);
#pragma unroll
        for (int r = 0; r < 4; ++r) {
            float w0 = __expf(s0[r]) * r0;
            float w1 = __expf(s1[r]) * r1;
            w16[wave][quad * 4 + r][n]      = (u16)(__float_as_uint(w0) >> 16);
            w16[wave][quad * 4 + r][16 + n] = (u16)(__float_as_uint(w1) >> 16);
        }
        asm volatile("s_waitcnt lgkmcnt(0)" ::: "memory");
        short8 aw = ld8(&w16[wave][n][quad * 8]);
        o = MFMA16(aw, th, o);
        o = MFMA16(aw, tl, o);
        if (c < 32) stchunk((c + 1) & 1);
        if (c < 31) ldchunk(c + 2);
        __syncthreads();
    }
    if (jt < 98) {
        float* ob = opart + (size_t)ih * 802816 + ((size_t)b * 1568 + (size_t)jt * 16) * 16;
#pragma unroll
        for (int r = 0; r < 4; ++r) ob[(quad * 4 + r) * 16 + n] = o[r];
    }
}

// ---------------------------------------------------------------------------
// LayerNorm over consecutive groups of 16 floats.
__global__ __launch_bounds__(256) void k_ln(const float* __restrict__ x,
                                            const float* __restrict__ gamma,
                                            const float* __restrict__ beta,
                                            float* __restrict__ out, int ngroups) {
    int g = blockIdx.x * 256 + threadIdx.x;
    if (g >= ngroups) return;
    const float4* xp = (const float4*)(x + (size_t)g * 16);
    float4 x0 = xp[0], x1 = xp[1], x2 = xp[2], x3 = xp[3];
    float sum = x0.x + x0.y + x0.z + x0.w + x1.x + x1.y + x1.z + x1.w
              + x2.x + x2.y + x2.z + x2.w + x3.x + x3.y + x3.z + x3.w;
    float mu = sum * 0.0625f;
    float var = 0.f;
    var += (x0.x-mu)*(x0.x-mu) + (x0.y-mu)*(x0.y-mu) + (x0.z-mu)*(x0.z-mu) + (x0.w-mu)*(x0.w-mu);
    var += (x1.x-mu)*(x1.x-mu) + (x1.y-mu)*(x1.y-mu) + (x1.z-mu)*(x1.z-mu) + (x1.w-mu)*(x1.w-mu);
    var += (x2.x-mu)*(x2.x-mu) + (x2.y-mu)*(x2.y-mu) + (x2.z-mu)*(x2.z-mu) + (x2.w-mu)*(x2.w-mu);
    var += (x3.x-mu)*(x3.x-mu) + (x3.y-mu)*(x3.y-mu) + (x3.z-mu)*(x3.z-mu) + (x3.w-mu)*(x3.w-mu);
    float rstd = rsqrtf(var * 0.0625f + 1e-5f);
    const float4* gp = (const float4*)gamma;
    const float4* bp = (const float4*)beta;
    float4 g0 = gp[0], g1 = gp[1], g2 = gp[2], g3 = gp[3];
    float4 be0 = bp[0], be1 = bp[1], be2 = bp[2], be3 = bp[3];
    float4 o0, o1, o2, o3;
    o0.x = (x0.x-mu)*rstd*g0.x + be0.x; o0.y = (x0.y-mu)*rstd*g0.y + be0.y;
    o0.z = (x0.z-mu)*rstd*g0.z + be0.z; o0.w = (x0.w-mu)*rstd*g0.w + be0.w;
    o1.x = (x1.x-mu)*rstd*g1.x + be1.x; o1.y = (x1.y-mu)*rstd*g1.y + be1.y;
    o1.z = (x1.z-mu)*rstd*g1.z + be1.z; o1.w = (x1.w-mu)*rstd*g1.w + be1.w;
    o2.x = (x2.x-mu)*rstd*g2.x + be2.x; o2.y = (x2.y-mu)*rstd*g2.y + be2.y;
    o2.z = (x2.z-mu)*rstd*g2.z + be2.z; o2.w = (x2.w-mu)*rstd*g2.w + be2.w;
    o3.x = (x3.x-mu)*rstd*g3.x + be3.x; o3.y = (x3.y-mu)*rstd*g3.y + be3.y;
    o3.z = (x3.z-mu)*rstd*g3.z + be3.z; o3.w = (x3.w-mu)*rstd*g3.w + be3.w;
    float4* op = (float4*)(out + (size_t)g * 16);
    op[0] = o0; op[1] = o1; op[2] = o2; op[3] = o3;
}

// ---------------------------------------------------------------------------
extern "C" void kernel_launch(void* const* d_in, const int* in_sizes, int n_in,
                              void* d_out, int out_size, void* d_ws, size_t ws_size,
                              hipStream_t stream) {
    const float* current_pose = (const float*)d_in[0];
    const float* next_pose    = (const float*)d_in[1];
    const float* current_w    = (const float*)d_in[2];
    const float* next_w       = (const float*)d_in[3];
    const float* E_proj       = (const float*)d_in[4];
    const float* rel          = (const float*)d_in[5];
    const float* ln_gamma     = (const float*)d_in[6];
    const float* ln_beta      = (const float*)d_in[7];
    float* out = (float*)d_out;
    float* ws  = (float*)d_ws;

    // workspace (floats); cpconv region reused by opart/dpart/conv2 after kproj2
    float* cpconv = ws;                 // 3,211,264
    float* conv2  = ws;                 // alias (written after cpconv last read)
    float* opart  = ws + 802816;        // 2 x 802,816 -> ends 2,408,448
    float* dpart  = ws + 2408448;       // 2 x 67,584 -> ends 2,543,616
    float* qconv  = ws + 3211264;       //   802,816 -> ends 4,014,080
    float* w2     = ws + 4014080;       //    73,728 -> ends 4,087,808
    u16*   ub     = (u16*)(ws + 4087808);
    u16* Qp  = ub;                      // 1,605,632
    u16* Kh  = ub + 1605632;            // 1,081,344
    u16* Kl  = ub + 2686976;
    u16* KhT = ub + 3768320;
    u16* KlT = ub + 4849664;
    u16* EhT = ub + 5931008;            // 458,752
    u16* ElT = ub + 6389760;            // ends 6,848,512 (~30.1 MB total)

    k_ecvt2 <<<72,   256, 0, stream>>>(E_proj, rel, current_w, EhT, ElT,
                                       Kh, Kl, KhT, KlT, w2);
    k_conv14<<<2048, 256, 0, stream>>>(current_pose, w2, cpconv);
    k_conv7 <<<2048, 64,  0, stream>>>(next_pose, next_pose, next_w, qconv, 1);
    k_cvt   <<<196,  256, 0, stream>>>(qconv, Qp);
    k_kproj2<<<1024, 256, 0, stream>>>(cpconv, EhT, ElT, Kh, Kl, KhT, KlT);
    k_stats4<<<1088, 256, 0, stream>>>(Qp, Kh, Kl, dpart);
    k_pv5   <<<1600, 256, 0, stream>>>(Qp, Kh, Kl, KhT, KlT, dpart, opart);
    k_conv7 <<<2048, 64,  0, stream>>>(opart, opart + 802816, next_w, conv2, 0);
    k_ln    <<<196,  256, 0, stream>>>(conv2, ln_gamma, ln_beta, out, 50176);
}